// Round 1
// baseline (2264.689 us; speedup 1.0000x reference)
//
#include <hip/hip_runtime.h>
#include <math.h>

#define B_   64
#define T_   200
#define DM   256
#define DI   512
#define NH   16
#define HD   32
#define DSZ  16
#define CD   544
#define DIP  1072
#define M_TOT (B_*T_)   // 12800
#define NCH_ 129

// ---------------- block-wide sum (blockDim.x in {128,256,512}, pow2) ---------
__device__ __forceinline__ float block_sum(float v, float* red) {
    int t = threadIdx.x;
    int nt = blockDim.x;
    red[t] = v;
    __syncthreads();
    for (int s = nt >> 1; s >= 64; s >>= 1) {
        if (t < s) red[t] += red[t + s];
        __syncthreads();
    }
    float r = 0.f;
    if (t < 64) {
        r = red[t];
        #pragma unroll
        for (int off = 32; off > 0; off >>= 1) r += __shfl_xor(r, off);
    }
    __syncthreads();
    if (t == 0) red[0] = r;
    __syncthreads();
    r = red[0];
    __syncthreads();
    return r;
}

// ---------------- emb mean over channels ------------------------------------
__global__ void emb_mean_k(const float* __restrict__ emb, float* __restrict__ em) {
    int d = threadIdx.x;
    float s = 0.f;
    for (int c = 0; c < NCH_; ++c) s += emb[c * DM + d];
    em[d] = s * (1.f / NCH_);
}

// ---------------- encoder depthwise conv (K=3, pad 1,1) -> xsT (M x 129) ----
__global__ void xsT_k(const float* __restrict__ x, const float* __restrict__ w,
                      const float* __restrict__ b, float* __restrict__ xsT) {
    int idx = blockIdx.x * blockDim.x + threadIdx.x;
    if (idx >= M_TOT * NCH_) return;
    int c = idx % NCH_;
    int m = idx / NCH_;
    int t = m % T_;
    int bb = m / T_;
    const float* xr = x + (size_t)(bb * NCH_ + c) * T_;
    float acc = b[c];
    if (t > 0)      acc += w[c*3+0] * xr[t-1];
    acc += w[c*3+1] * xr[t];
    if (t < T_-1)   acc += w[c*3+2] * xr[t+1];
    xsT[idx] = acc;
}

// ---------------- generic fp32 GEMM: C[M,N] = A[M,K] * B[N,K]^T -------------
__global__ __launch_bounds__(256) void gemm_nt(const float* __restrict__ A,
                                               const float* __restrict__ B,
                                               float* __restrict__ C,
                                               int M, int N, int K) {
    __shared__ float As[16][64 + 1];
    __shared__ float Bs[16][64 + 1];
    int bm = blockIdx.y * 64, bn = blockIdx.x * 64;
    int tid = threadIdx.x;
    int tx = tid & 15, ty = tid >> 4;
    float acc[4][4] = {};
    for (int k0 = 0; k0 < K; k0 += 16) {
        #pragma unroll
        for (int j = 0; j < 4; ++j) {
            int i = tid * 4 + j;
            int mm = i >> 4, kk = i & 15;
            int gk = k0 + kk;
            int gm = bm + mm;
            As[kk][mm] = (gm < M && gk < K) ? A[(size_t)gm * K + gk] : 0.f;
            int gn = bn + mm;
            Bs[kk][mm] = (gn < N && gk < K) ? B[(size_t)gn * K + gk] : 0.f;
        }
        __syncthreads();
        #pragma unroll
        for (int kk = 0; kk < 16; ++kk) {
            float a[4], b[4];
            #pragma unroll
            for (int i = 0; i < 4; ++i) a[i] = As[kk][ty * 4 + i];
            #pragma unroll
            for (int j = 0; j < 4; ++j) b[j] = Bs[kk][tx * 4 + j];
            #pragma unroll
            for (int i = 0; i < 4; ++i)
                #pragma unroll
                for (int j = 0; j < 4; ++j)
                    acc[i][j] += a[i] * b[j];
        }
        __syncthreads();
    }
    #pragma unroll
    for (int i = 0; i < 4; ++i) {
        int gm = bm + ty * 4 + i;
        if (gm >= M) continue;
        #pragma unroll
        for (int j = 0; j < 4; ++j) {
            int gn = bn + tx * 4 + j;
            if (gn < N) C[(size_t)gm * N + gn] = acc[i][j];
        }
    }
}

// ---------------- encoder: + mixer_b + emb_mean, then LayerNorm -------------
__global__ __launch_bounds__(DM) void enc_ln_k(float* __restrict__ h,
        const float* __restrict__ mb, const float* __restrict__ em,
        const float* __restrict__ w, const float* __restrict__ bb) {
    __shared__ float red[DM];
    int m = blockIdx.x, d = threadIdx.x;
    float v = h[(size_t)m * DM + d] + mb[d] + em[d];
    float mean = block_sum(v, red) * (1.f / DM);
    float dv = v - mean;
    float var = block_sum(dv * dv, red) * (1.f / DM);
    h[(size_t)m * DM + d] = dv * rsqrtf(var + 1e-5f) * w[d] + bb[d];
}

// ---------------- dt = softplus(dt_raw + dt_bias) ---------------------------
__global__ void dt_k(const float* __restrict__ zx, const float* __restrict__ dtb_in,
                     float* __restrict__ dtb) {
    int idx = blockIdx.x * blockDim.x + threadIdx.x;
    if (idx >= M_TOT * NH) return;
    int hh = idx % NH;
    int m = idx / NH;
    float xv = zx[(size_t)m * DIP + (DI + CD) + hh] + dtb_in[hh];
    float sp = (xv > 20.f) ? xv : log1pf(expf(xv));
    dtb[idx] = sp;
}

// ---------------- causal depthwise conv (K=4) + silu on xBC -----------------
__global__ void conv_k(const float* __restrict__ zx, const float* __restrict__ cw,
                       const float* __restrict__ cb, float* __restrict__ xbc) {
    int idx = blockIdx.x * blockDim.x + threadIdx.x;
    if (idx >= M_TOT * CD) return;
    int c = idx % CD;
    int m = idx / CD;
    int t = m % T_;
    float acc = cb[c];
    #pragma unroll
    for (int k = 0; k < 4; ++k) {
        int tt = t - 3 + k;
        if (tt >= 0) acc += cw[c*4+k] * zx[(size_t)(m - (3 - k)) * DIP + DI + c];
    }
    float s = acc / (1.f + expf(-acc));
    xbc[idx] = s;
}

// ---------------- selective state scan: block=(b,h), thread=(p,n) -----------
__global__ __launch_bounds__(512) void scan_k(const float* __restrict__ xbc,
        const float* __restrict__ dtb, const float* __restrict__ A_log,
        const float* __restrict__ D_skip, float* __restrict__ y) {
    int bh = blockIdx.x;
    int b = bh >> 4;
    int h = bh & 15;
    int tid = threadIdx.x;
    int p = tid >> 4;
    int n = tid & 15;
    float A = -expf(A_log[h]);
    float Dh = D_skip[h];
    float s = 0.f;
    int base = b * T_;
    for (int t = 0; t < T_; ++t) {
        int m = base + t;
        const float* row = xbc + (size_t)m * CD;
        float dt = dtb[m * NH + h];
        float xh = row[h * HD + p];
        float Bn = row[DI + n];
        float Cn = row[DI + DSZ + n];
        float dA = expf(dt * A);
        s = dA * s + dt * xh * Bn;
        float yv = s * Cn;
        yv += __shfl_xor(yv, 1);
        yv += __shfl_xor(yv, 2);
        yv += __shfl_xor(yv, 4);
        yv += __shfl_xor(yv, 8);
        if (n == 0) y[(size_t)m * DI + h * HD + p] = yv + Dh * xh;
    }
}

// ---------------- y = y*silu(z); RMSNorm(y)*norm_w (in place) ---------------
__global__ __launch_bounds__(DI) void gate_rms_k(float* __restrict__ y,
        const float* __restrict__ zx, const float* __restrict__ nw) {
    __shared__ float red[DI];
    int m = blockIdx.x, e = threadIdx.x;
    float yv = y[(size_t)m * DI + e];
    float z = zx[(size_t)m * DIP + e];
    float g = yv * (z / (1.f + expf(-z)));
    float ssum = block_sum(g * g, red);
    float r = rsqrtf(ssum * (1.f / DI) + 1e-5f);
    y[(size_t)m * DI + e] = g * r * nw[e];
}

// ---------------- h = LayerNorm(c + h) (in place on h) ----------------------
__global__ __launch_bounds__(DM) void add_ln_k(float* __restrict__ h,
        const float* __restrict__ c, const float* __restrict__ w,
        const float* __restrict__ bb) {
    __shared__ float red[DM];
    int m = blockIdx.x, d = threadIdx.x;
    float v = c[(size_t)m * DM + d] + h[(size_t)m * DM + d];
    float mean = block_sum(v, red) * (1.f / DM);
    float dv = v - mean;
    float var = block_sum(dv * dv, red) * (1.f / DM);
    h[(size_t)m * DM + d] = dv * rsqrtf(var + 1e-5f) * w[d] + bb[d];
}

// ---------------- mean over time -------------------------------------------
__global__ __launch_bounds__(DM) void pool_k(const float* __restrict__ h,
                                             float* __restrict__ pooled) {
    int b = blockIdx.x, d = threadIdx.x;
    float s = 0.f;
    for (int t = 0; t < T_; ++t) s += h[(size_t)(b * T_ + t) * DM + d];
    pooled[b * DM + d] = s * (1.f / T_);
}

// ---------------- head: relu(pooled@W1^T+b1)@W2^T + b2 ----------------------
__global__ __launch_bounds__(128) void head_k(const float* __restrict__ pooled,
        const float* __restrict__ w1, const float* __restrict__ b1,
        const float* __restrict__ w2, const float* __restrict__ b2,
        float* __restrict__ out) {
    __shared__ float red[128];
    int b = blockIdx.x, j = threadIdx.x;
    const float* pr = pooled + b * DM;
    float acc = b1[j];
    for (int d = 0; d < DM; ++d) acc += pr[d] * w1[j * DM + d];
    float hid = fmaxf(acc, 0.f);
    float v = hid * w2[j];
    float s = block_sum(v, red);
    if (j == 0) out[b] = s + b2[0];
}

extern "C" void kernel_launch(void* const* d_in, const int* in_sizes, int n_in,
                              void* d_out, int out_size, void* d_ws, size_t ws_size,
                              hipStream_t stream) {
    const float* x         = (const float*)d_in[0];
    const float* emb       = (const float*)d_in[1];
    const float* sconv_w   = (const float*)d_in[2];
    const float* sconv_b   = (const float*)d_in[3];
    const float* mixer_w   = (const float*)d_in[4];
    const float* mixer_b   = (const float*)d_in[5];
    const float* enc_ln_w  = (const float*)d_in[6];
    const float* enc_ln_b  = (const float*)d_in[7];
    const float* in_proj_w = (const float*)d_in[8];
    const float* conv_w    = (const float*)d_in[9];
    const float* conv_b    = (const float*)d_in[10];
    const float* dt_bias   = (const float*)d_in[11];
    const float* A_log     = (const float*)d_in[12];
    const float* D_skip    = (const float*)d_in[13];
    const float* norm_w    = (const float*)d_in[14];
    const float* out_proj_w= (const float*)d_in[15];
    const float* ln_w      = (const float*)d_in[16];
    const float* ln_b      = (const float*)d_in[17];
    const float* head1_w   = (const float*)d_in[18];
    const float* head1_b   = (const float*)d_in[19];
    const float* head2_w   = (const float*)d_in[20];
    const float* head2_b   = (const float*)d_in[21];
    float* out = (float*)d_out;

    float* ws  = (float*)d_ws;
    float* h   = ws;                          // M*DM    = 3,276,800
    float* zx  = h   + (size_t)M_TOT * DM;    // M*DIP   = 13,721,600
    float* xbc = zx  + (size_t)M_TOT * DIP;   // M*CD    = 6,963,200
    float* dtb = xbc + (size_t)M_TOT * CD;    // M*NH    = 204,800
    float* y   = dtb + (size_t)M_TOT * NH;    // M*DI    = 6,553,600
    float* em  = y   + (size_t)M_TOT * DI;    // 256
    float* pooled = em + 256;                 // 16,384
    float* xsT = y;   // alias: xsT only used before any layer touches y

    emb_mean_k<<<1, DM, 0, stream>>>(emb, em);
    {
        int n = M_TOT * NCH_;
        xsT_k<<<(n + 255) / 256, 256, 0, stream>>>(x, sconv_w, sconv_b, xsT);
    }
    gemm_nt<<<dim3(4, 200), 256, 0, stream>>>(xsT, mixer_w, h, M_TOT, DM, NCH_);
    enc_ln_k<<<M_TOT, DM, 0, stream>>>(h, mixer_b, em, enc_ln_w, enc_ln_b);

    for (int l = 0; l < 4; ++l) {
        gemm_nt<<<dim3(17, 200), 256, 0, stream>>>(
            h, in_proj_w + (size_t)l * DIP * DM, zx, M_TOT, DIP, DM);
        {
            int n = M_TOT * NH;
            dt_k<<<(n + 255) / 256, 256, 0, stream>>>(zx, dt_bias + l * NH, dtb);
        }
        {
            int n = M_TOT * CD;
            conv_k<<<(n + 255) / 256, 256, 0, stream>>>(
                zx, conv_w + l * CD * 4, conv_b + l * CD, xbc);
        }
        scan_k<<<B_ * NH, 512, 0, stream>>>(xbc, dtb, A_log + l * NH, D_skip + l * NH, y);
        gate_rms_k<<<M_TOT, DI, 0, stream>>>(y, zx, norm_w + l * DI);
        gemm_nt<<<dim3(4, 200), 256, 0, stream>>>(
            y, out_proj_w + (size_t)l * DM * DI, zx, M_TOT, DM, DI);
        add_ln_k<<<M_TOT, DM, 0, stream>>>(h, zx, ln_w + l * DM, ln_b + l * DM);
    }

    pool_k<<<B_, DM, 0, stream>>>(h, pooled);
    head_k<<<B_, 128, 0, stream>>>(pooled, head1_w, head1_b, head2_w, head2_b, out);
}

// Round 2
// 1207.236 us; speedup vs baseline: 1.8759x; 1.8759x over previous
//
#include <hip/hip_runtime.h>
#include <math.h>

#define B_   64
#define T_   200
#define DM   256
#define DI   512
#define NH   16
#define HD   32
#define DSZ  16
#define CD   544
#define DIP  1072
#define M_TOT (B_*T_)   // 12800
#define NCH_ 129

typedef unsigned short u16;
typedef unsigned int u32;
typedef __attribute__((ext_vector_type(8))) short short8;   // 8 bf16 (4 VGPRs)
typedef __attribute__((ext_vector_type(4))) float f32x4;

// ---------------- block-wide sum (blockDim.x in {128,256,512}, pow2) ---------
__device__ __forceinline__ float block_sum(float v, float* red) {
    int t = threadIdx.x;
    int nt = blockDim.x;
    red[t] = v;
    __syncthreads();
    for (int s = nt >> 1; s >= 64; s >>= 1) {
        if (t < s) red[t] += red[t + s];
        __syncthreads();
    }
    float r = 0.f;
    if (t < 64) {
        r = red[t];
        #pragma unroll
        for (int off = 32; off > 0; off >>= 1) r += __shfl_xor(r, off);
    }
    __syncthreads();
    if (t == 0) red[0] = r;
    __syncthreads();
    r = red[0];
    __syncthreads();
    return r;
}

// ---------------- bf16 split helpers ----------------------------------------
__device__ __forceinline__ u16 f2bf_rn(float f) {
    u32 u = __float_as_uint(f);
    u32 r = (u + 0x7fffu + ((u >> 16) & 1u)) >> 16;
    return (u16)r;
}
__device__ __forceinline__ float bf2f(u16 h) {
    return __uint_as_float(((u32)h) << 16);
}

// ---------------- emb mean over channels ------------------------------------
__global__ void emb_mean_k(const float* __restrict__ emb, float* __restrict__ em) {
    int d = threadIdx.x;
    float s = 0.f;
    for (int c = 0; c < NCH_; ++c) s += emb[c * DM + d];
    em[d] = s * (1.f / NCH_);
}

// ---------------- encoder depthwise conv (K=3, pad 1,1) -> xsT (M x 129) ----
__global__ void xsT_k(const float* __restrict__ x, const float* __restrict__ w,
                      const float* __restrict__ b, float* __restrict__ xsT) {
    int idx = blockIdx.x * blockDim.x + threadIdx.x;
    if (idx >= M_TOT * NCH_) return;
    int c = idx % NCH_;
    int m = idx / NCH_;
    int t = m % T_;
    int bb = m / T_;
    const float* xr = x + (size_t)(bb * NCH_ + c) * T_;
    float acc = b[c];
    if (t > 0)      acc += w[c*3+0] * xr[t-1];
    acc += w[c*3+1] * xr[t];
    if (t < T_-1)   acc += w[c*3+2] * xr[t+1];
    xsT[idx] = acc;
}

// ---------------- generic fp32 GEMM (encoder + fallback) --------------------
__global__ __launch_bounds__(256) void gemm_nt(const float* __restrict__ A,
                                               const float* __restrict__ B,
                                               float* __restrict__ C,
                                               int M, int N, int K) {
    __shared__ float As[16][64 + 1];
    __shared__ float Bs[16][64 + 1];
    int bm = blockIdx.y * 64, bn = blockIdx.x * 64;
    int tid = threadIdx.x;
    int tx = tid & 15, ty = tid >> 4;
    float acc[4][4] = {};
    for (int k0 = 0; k0 < K; k0 += 16) {
        #pragma unroll
        for (int j = 0; j < 4; ++j) {
            int i = tid * 4 + j;
            int mm = i >> 4, kk = i & 15;
            int gk = k0 + kk;
            int gm = bm + mm;
            As[kk][mm] = (gm < M && gk < K) ? A[(size_t)gm * K + gk] : 0.f;
            int gn = bn + mm;
            Bs[kk][mm] = (gn < N && gk < K) ? B[(size_t)gn * K + gk] : 0.f;
        }
        __syncthreads();
        #pragma unroll
        for (int kk = 0; kk < 16; ++kk) {
            float a[4], b[4];
            #pragma unroll
            for (int i = 0; i < 4; ++i) a[i] = As[kk][ty * 4 + i];
            #pragma unroll
            for (int j = 0; j < 4; ++j) b[j] = Bs[kk][tx * 4 + j];
            #pragma unroll
            for (int i = 0; i < 4; ++i)
                #pragma unroll
                for (int j = 0; j < 4; ++j)
                    acc[i][j] += a[i] * b[j];
        }
        __syncthreads();
    }
    #pragma unroll
    for (int i = 0; i < 4; ++i) {
        int gm = bm + ty * 4 + i;
        if (gm >= M) continue;
        #pragma unroll
        for (int j = 0; j < 4; ++j) {
            int gn = bn + tx * 4 + j;
            if (gn < N) C[(size_t)gm * N + gn] = acc[i][j];
        }
    }
}

// ---------------- pack fp32 -> bf16x3 (A side: [hi | hi | lo]) --------------
__global__ void pack_a3_k(const float* __restrict__ A, u16* __restrict__ A3,
                          int MK, int K) {
    int idx = blockIdx.x * blockDim.x + threadIdx.x;
    if (idx >= MK) return;
    int k = idx % K, m = idx / K;
    float a = A[idx];
    u16 hi = f2bf_rn(a);
    u16 lo = f2bf_rn(a - bf2f(hi));
    u16* row = A3 + (size_t)m * 3 * K;
    row[k] = hi;
    row[K + k] = hi;
    row[2 * K + k] = lo;
}

// ---------------- pack fp32 -> bf16x3 (B side: [hi | lo | hi], row-padded) --
__global__ void pack_b3_k(const float* __restrict__ Bm, u16* __restrict__ B3,
                          int N, int Npad, int K) {
    int idx = blockIdx.x * blockDim.x + threadIdx.x;
    if (idx >= Npad * K) return;
    int k = idx % K, n = idx / K;
    u16 hi = 0, lo = 0;
    if (n < N) {
        float b = Bm[(size_t)n * K + k];
        hi = f2bf_rn(b);
        lo = f2bf_rn(b - bf2f(hi));
    }
    u16* row = B3 + (size_t)n * 3 * K;
    row[k] = hi;
    row[K + k] = lo;
    row[2 * K + k] = hi;
}

// ---------------- MFMA bf16 GEMM: C[M,ldc](cols<Nreal) = A3[M,K3]*B3[.,K3]^T
// BM=128, BN=64, BK=64, 256 threads (4 waves, 2x2), XOR-swizzled LDS.
__global__ __launch_bounds__(256) void gemm_mfma(const u16* __restrict__ A3,
                                                 const u16* __restrict__ B3,
                                                 float* __restrict__ C,
                                                 int K3, int ldc, int Nreal) {
    __shared__ u16 As[128 * 64];
    __shared__ u16 Bs[64 * 64];
    int tid = threadIdx.x;
    int lane = tid & 63;
    int wave = tid >> 6;
    int wr = wave >> 1;
    int wc = wave & 1;
    int bm = blockIdx.y * 128;
    int bn = blockIdx.x * 64;

    f32x4 acc[4][2] = {};

    const size_t ldA = (size_t)K3 * 2;   // bytes per row

    for (int k0 = 0; k0 < K3; k0 += 64) {
        // stage A tile (128 rows x 128 B), linear LDS, source pre-swizzled
        #pragma unroll
        for (int c = 0; c < 4; ++c) {
            int o = c * 4096 + tid * 16;
            int row = o >> 7;
            int slot = (o >> 4) & 7;
            int sslot = slot ^ (row & 7);
            const char* src = (const char*)A3 + (size_t)(bm + row) * ldA
                              + (size_t)k0 * 2 + sslot * 16;
            __builtin_amdgcn_global_load_lds(
                (const __attribute__((address_space(1))) u32*)src,
                (__attribute__((address_space(3))) u32*)((char*)As + o),
                16, 0, 0);
        }
        // stage B tile (64 rows x 128 B)
        #pragma unroll
        for (int c = 0; c < 2; ++c) {
            int o = c * 4096 + tid * 16;
            int row = o >> 7;
            int slot = (o >> 4) & 7;
            int sslot = slot ^ (row & 7);
            const char* src = (const char*)B3 + (size_t)(bn + row) * ldA
                              + (size_t)k0 * 2 + sslot * 16;
            __builtin_amdgcn_global_load_lds(
                (const __attribute__((address_space(1))) u32*)src,
                (__attribute__((address_space(3))) u32*)((char*)Bs + o),
                16, 0, 0);
        }
        __syncthreads();
        #pragma unroll
        for (int kk = 0; kk < 2; ++kk) {
            int lslot = kk * 4 + (lane >> 4);
            short8 bfr[2];
            #pragma unroll
            for (int n = 0; n < 2; ++n) {
                int row = wc * 32 + n * 16 + (lane & 15);
                int pslot = lslot ^ (row & 7);
                bfr[n] = *(const short8*)((const char*)Bs + row * 128 + pslot * 16);
            }
            #pragma unroll
            for (int m = 0; m < 4; ++m) {
                int row = wr * 64 + m * 16 + (lane & 15);
                int pslot = lslot ^ (row & 7);
                short8 afr = *(const short8*)((const char*)As + row * 128 + pslot * 16);
                acc[m][0] = __builtin_amdgcn_mfma_f32_16x16x32_bf16(afr, bfr[0], acc[m][0], 0, 0, 0);
                acc[m][1] = __builtin_amdgcn_mfma_f32_16x16x32_bf16(afr, bfr[1], acc[m][1], 0, 0, 0);
            }
        }
        __syncthreads();
    }

    int crow0 = bm + wr * 64;
    int ccol0 = bn + wc * 32;
    #pragma unroll
    for (int m = 0; m < 4; ++m) {
        #pragma unroll
        for (int n = 0; n < 2; ++n) {
            int col = ccol0 + n * 16 + (lane & 15);
            if (col < Nreal) {
                #pragma unroll
                for (int j = 0; j < 4; ++j) {
                    int rrow = crow0 + m * 16 + (lane >> 4) * 4 + j;
                    C[(size_t)rrow * ldc + col] = acc[m][n][j];
                }
            }
        }
    }
}

// ---------------- encoder: + mixer_b + emb_mean, then LayerNorm -------------
__global__ __launch_bounds__(DM) void enc_ln_k(float* __restrict__ h,
        const float* __restrict__ mb, const float* __restrict__ em,
        const float* __restrict__ w, const float* __restrict__ bb) {
    __shared__ float red[DM];
    int m = blockIdx.x, d = threadIdx.x;
    float v = h[(size_t)m * DM + d] + mb[d] + em[d];
    float mean = block_sum(v, red) * (1.f / DM);
    float dv = v - mean;
    float var = block_sum(dv * dv, red) * (1.f / DM);
    h[(size_t)m * DM + d] = dv * rsqrtf(var + 1e-5f) * w[d] + bb[d];
}

// ---------------- dt = softplus(dt_raw + dt_bias) ---------------------------
__global__ void dt_k(const float* __restrict__ zx, const float* __restrict__ dtb_in,
                     float* __restrict__ dtb) {
    int idx = blockIdx.x * blockDim.x + threadIdx.x;
    if (idx >= M_TOT * NH) return;
    int hh = idx % NH;
    int m = idx / NH;
    float xv = zx[(size_t)m * DIP + (DI + CD) + hh] + dtb_in[hh];
    float sp = (xv > 20.f) ? xv : log1pf(expf(xv));
    dtb[idx] = sp;
}

// ---------------- causal depthwise conv (K=4) + silu on xBC -----------------
__global__ void conv_k(const float* __restrict__ zx, const float* __restrict__ cw,
                       const float* __restrict__ cb, float* __restrict__ xbc) {
    int idx = blockIdx.x * blockDim.x + threadIdx.x;
    if (idx >= M_TOT * CD) return;
    int c = idx % CD;
    int m = idx / CD;
    int t = m % T_;
    float acc = cb[c];
    #pragma unroll
    for (int k = 0; k < 4; ++k) {
        int tt = t - 3 + k;
        if (tt >= 0) acc += cw[c*4+k] * zx[(size_t)(m - (3 - k)) * DIP + DI + c];
    }
    float s = acc / (1.f + expf(-acc));
    xbc[idx] = s;
}

// ---------------- selective state scan: block=(b,h), thread=(p,n) -----------
__global__ __launch_bounds__(512) void scan_k(const float* __restrict__ xbc,
        const float* __restrict__ dtb, const float* __restrict__ A_log,
        const float* __restrict__ D_skip, float* __restrict__ y) {
    int bh = blockIdx.x;
    int b = bh >> 4;
    int h = bh & 15;
    int tid = threadIdx.x;
    int p = tid >> 4;
    int n = tid & 15;
    float A = -expf(A_log[h]);
    float Dh = D_skip[h];
    float s = 0.f;
    int base = b * T_;
    for (int t = 0; t < T_; ++t) {
        int m = base + t;
        const float* row = xbc + (size_t)m * CD;
        float dt = dtb[m * NH + h];
        float xh = row[h * HD + p];
        float Bn = row[DI + n];
        float Cn = row[DI + DSZ + n];
        float dA = expf(dt * A);
        s = dA * s + dt * xh * Bn;
        float yv = s * Cn;
        yv += __shfl_xor(yv, 1);
        yv += __shfl_xor(yv, 2);
        yv += __shfl_xor(yv, 4);
        yv += __shfl_xor(yv, 8);
        if (n == 0) y[(size_t)m * DI + h * HD + p] = yv + Dh * xh;
    }
}

// ---------------- y = y*silu(z); RMSNorm(y)*norm_w (in place) ---------------
__global__ __launch_bounds__(DI) void gate_rms_k(float* __restrict__ y,
        const float* __restrict__ zx, const float* __restrict__ nw) {
    __shared__ float red[DI];
    int m = blockIdx.x, e = threadIdx.x;
    float yv = y[(size_t)m * DI + e];
    float z = zx[(size_t)m * DIP + e];
    float g = yv * (z / (1.f + expf(-z)));
    float ssum = block_sum(g * g, red);
    float r = rsqrtf(ssum * (1.f / DI) + 1e-5f);
    y[(size_t)m * DI + e] = g * r * nw[e];
}

// ---------------- h = LayerNorm(c + h) (in place on h) ----------------------
__global__ __launch_bounds__(DM) void add_ln_k(float* __restrict__ h,
        const float* __restrict__ c, const float* __restrict__ w,
        const float* __restrict__ bb) {
    __shared__ float red[DM];
    int m = blockIdx.x, d = threadIdx.x;
    float v = c[(size_t)m * DM + d] + h[(size_t)m * DM + d];
    float mean = block_sum(v, red) * (1.f / DM);
    float dv = v - mean;
    float var = block_sum(dv * dv, red) * (1.f / DM);
    h[(size_t)m * DM + d] = dv * rsqrtf(var + 1e-5f) * w[d] + bb[d];
}

// ---------------- mean over time -------------------------------------------
__global__ __launch_bounds__(DM) void pool_k(const float* __restrict__ h,
                                             float* __restrict__ pooled) {
    int b = blockIdx.x, d = threadIdx.x;
    float s = 0.f;
    for (int t = 0; t < T_; ++t) s += h[(size_t)(b * T_ + t) * DM + d];
    pooled[b * DM + d] = s * (1.f / T_);
}

// ---------------- head: relu(pooled@W1^T+b1)@W2^T + b2 ----------------------
__global__ __launch_bounds__(128) void head_k(const float* __restrict__ pooled,
        const float* __restrict__ w1, const float* __restrict__ b1,
        const float* __restrict__ w2, const float* __restrict__ b2,
        float* __restrict__ out) {
    __shared__ float red[128];
    int b = blockIdx.x, j = threadIdx.x;
    const float* pr = pooled + b * DM;
    float acc = b1[j];
    for (int d = 0; d < DM; ++d) acc += pr[d] * w1[j * DM + d];
    float hid = fmaxf(acc, 0.f);
    float v = hid * w2[j];
    float s = block_sum(v, red);
    if (j == 0) out[b] = s + b2[0];
}

extern "C" void kernel_launch(void* const* d_in, const int* in_sizes, int n_in,
                              void* d_out, int out_size, void* d_ws, size_t ws_size,
                              hipStream_t stream) {
    const float* x         = (const float*)d_in[0];
    const float* emb       = (const float*)d_in[1];
    const float* sconv_w   = (const float*)d_in[2];
    const float* sconv_b   = (const float*)d_in[3];
    const float* mixer_w   = (const float*)d_in[4];
    const float* mixer_b   = (const float*)d_in[5];
    const float* enc_ln_w  = (const float*)d_in[6];
    const float* enc_ln_b  = (const float*)d_in[7];
    const float* in_proj_w = (const float*)d_in[8];
    const float* conv_w    = (const float*)d_in[9];
    const float* conv_b    = (const float*)d_in[10];
    const float* dt_bias   = (const float*)d_in[11];
    const float* A_log     = (const float*)d_in[12];
    const float* D_skip    = (const float*)d_in[13];
    const float* norm_w    = (const float*)d_in[14];
    const float* out_proj_w= (const float*)d_in[15];
    const float* ln_w      = (const float*)d_in[16];
    const float* ln_b      = (const float*)d_in[17];
    const float* head1_w   = (const float*)d_in[18];
    const float* head1_b   = (const float*)d_in[19];
    const float* head2_w   = (const float*)d_in[20];
    const float* head2_b   = (const float*)d_in[21];
    float* out = (float*)d_out;

    float* ws  = (float*)d_ws;
    float* h   = ws;                          // M*DM    = 3,276,800
    float* zx  = h   + (size_t)M_TOT * DM;    // M*DIP   = 13,721,600
    float* xbc = zx  + (size_t)M_TOT * DIP;   // M*CD    = 6,963,200
    float* dtb = xbc + (size_t)M_TOT * CD;    // M*NH    = 204,800
    float* y   = dtb + (size_t)M_TOT * NH;    // M*DI    = 6,553,600
    float* em  = y   + (size_t)M_TOT * DI;    // 256
    float* pooled = em + 256;                 // 16,384
    float* xsT = y;   // alias: xsT only used before any layer touches y

    u16* A3 = (u16*)(pooled + 16384);                 // max 12800*1536 u16
    u16* B3 = A3 + (size_t)12800 * 1536;              // max 1088*768 u16
    size_t need_bytes = ((size_t)(3276800 + 13721600 + 6963200 + 204800 +
                                  6553600 + 256 + 16384) * 4)
                        + ((size_t)12800 * 1536 + 1088 * 768) * 2;
    bool fast = ws_size >= need_bytes;

    emb_mean_k<<<1, DM, 0, stream>>>(emb, em);
    {
        int n = M_TOT * NCH_;
        xsT_k<<<(n + 255) / 256, 256, 0, stream>>>(x, sconv_w, sconv_b, xsT);
    }
    gemm_nt<<<dim3(4, 200), 256, 0, stream>>>(xsT, mixer_w, h, M_TOT, DM, NCH_);
    enc_ln_k<<<M_TOT, DM, 0, stream>>>(h, mixer_b, em, enc_ln_w, enc_ln_b);

    for (int l = 0; l < 4; ++l) {
        if (fast) {
            // ---- in_proj: bf16x3 MFMA, K=256 -> K3=768, N=1072 (pad 1088)
            pack_a3_k<<<(M_TOT * DM + 255) / 256, 256, 0, stream>>>(h, A3, M_TOT * DM, DM);
            pack_b3_k<<<(1088 * DM + 255) / 256, 256, 0, stream>>>(
                in_proj_w + (size_t)l * DIP * DM, B3, DIP, 1088, DM);
            gemm_mfma<<<dim3(17, 100), 256, 0, stream>>>(A3, B3, zx, 768, DIP, DIP);
        } else {
            gemm_nt<<<dim3(17, 200), 256, 0, stream>>>(
                h, in_proj_w + (size_t)l * DIP * DM, zx, M_TOT, DIP, DM);
        }
        {
            int n = M_TOT * NH;
            dt_k<<<(n + 255) / 256, 256, 0, stream>>>(zx, dt_bias + l * NH, dtb);
        }
        {
            int n = M_TOT * CD;
            conv_k<<<(n + 255) / 256, 256, 0, stream>>>(
                zx, conv_w + l * CD * 4, conv_b + l * CD, xbc);
        }
        scan_k<<<B_ * NH, 512, 0, stream>>>(xbc, dtb, A_log + l * NH, D_skip + l * NH, y);
        gate_rms_k<<<M_TOT, DI, 0, stream>>>(y, zx, norm_w + l * DI);
        if (fast) {
            // ---- out_proj: K=512 -> K3=1536, N=256
            pack_a3_k<<<(M_TOT * DI + 255) / 256, 256, 0, stream>>>(y, A3, M_TOT * DI, DI);
            pack_b3_k<<<(DM * DI + 255) / 256, 256, 0, stream>>>(
                out_proj_w + (size_t)l * DM * DI, B3, DM, DM, DI);
            gemm_mfma<<<dim3(4, 100), 256, 0, stream>>>(A3, B3, zx, 1536, DM, DM);
        } else {
            gemm_nt<<<dim3(4, 200), 256, 0, stream>>>(
                y, out_proj_w + (size_t)l * DM * DI, zx, M_TOT, DM, DI);
        }
        add_ln_k<<<M_TOT, DM, 0, stream>>>(h, zx, ln_w + l * DM, ln_b + l * DM);
    }

    pool_k<<<B_, DM, 0, stream>>>(h, pooled);
    head_k<<<B_, 128, 0, stream>>>(pooled, head1_w, head1_b, head2_w, head2_b, out);
}

// Round 3
// 998.358 us; speedup vs baseline: 2.2684x; 1.2092x over previous
//
#include <hip/hip_runtime.h>
#include <math.h>

#define B_   64
#define T_   200
#define DM   256
#define DI   512
#define NH   16
#define HD   32
#define DSZ  16
#define CD   544
#define DIP  1072
#define M_TOT (B_*T_)   // 12800
#define NCH_ 129
#define KENC 192        // encoder K padded (129 -> 192, 3*192 = 576 = 9*64)

typedef unsigned short u16;
typedef unsigned int u32;
typedef __attribute__((ext_vector_type(8))) short short8;   // 8 bf16
typedef __attribute__((ext_vector_type(4))) short short4v;  // 4 bf16
typedef __attribute__((ext_vector_type(4))) float f32x4;

// ---------------- helpers ----------------------------------------------------
__device__ __forceinline__ float wave_sum(float v) {
    #pragma unroll
    for (int off = 32; off > 0; off >>= 1) v += __shfl_xor(v, off);
    return v;
}
__device__ __forceinline__ u16 f2bf_rn(float f) {
    u32 u = __float_as_uint(f);
    u32 r = (u + 0x7fffu + ((u >> 16) & 1u)) >> 16;
    return (u16)r;
}
__device__ __forceinline__ float bf2f(u16 h) {
    return __uint_as_float(((u32)h) << 16);
}
__device__ __forceinline__ void split_bf(float a, u16& hi, u16& lo) {
    hi = f2bf_rn(a);
    lo = f2bf_rn(a - bf2f(hi));
}

// ---------------- emb mean over channels ------------------------------------
__global__ void emb_mean_k(const float* __restrict__ emb, float* __restrict__ em) {
    int d = threadIdx.x;
    float s = 0.f;
    for (int c = 0; c < NCH_; ++c) s += emb[c * DM + d];
    em[d] = s * (1.f / NCH_);
}

// ---------------- encoder dwconv (K=3) -> A3 [M x 3*KENC] (hi|hi|lo) --------
__global__ void xsA3_k(const float* __restrict__ x, const float* __restrict__ w,
                       const float* __restrict__ b, u16* __restrict__ A3) {
    int idx = blockIdx.x * blockDim.x + threadIdx.x;
    if (idx >= M_TOT * KENC) return;
    int c = idx % KENC;
    int m = idx / KENC;
    float acc = 0.f;
    if (c < NCH_) {
        int t = m % T_;
        int bb = m / T_;
        const float* xr = x + (size_t)(bb * NCH_ + c) * T_;
        acc = b[c];
        if (t > 0)      acc += w[c*3+0] * xr[t-1];
        acc += w[c*3+1] * xr[t];
        if (t < T_-1)   acc += w[c*3+2] * xr[t+1];
    }
    u16 hi, lo; split_bf(acc, hi, lo);
    u16* row = A3 + (size_t)m * (3*KENC);
    row[c] = hi; row[KENC + c] = hi; row[2*KENC + c] = lo;
}

// ---------------- pack weights fp32 -> bf16x3 [hi | lo | hi] ----------------
__global__ void pack_b3_k(const float* __restrict__ Bm, u16* __restrict__ B3,
                          int N, int Npad, int Kreal, int K) {
    int idx = blockIdx.x * blockDim.x + threadIdx.x;
    if (idx >= Npad * K) return;
    int k = idx % K, n = idx / K;
    u16 hi = 0, lo = 0;
    if (n < N && k < Kreal) {
        float b = Bm[(size_t)n * Kreal + k];
        split_bf(b, hi, lo);
    }
    u16* row = B3 + (size_t)n * 3 * K;
    row[k] = hi;
    row[K + k] = lo;
    row[2 * K + k] = hi;
}

// ---------------- MFMA bf16 GEMM: C[M,ldc](cols<Nreal) = A3[M,K3]*B3[.,K3]^T
// BM=128, BN=64, BK=64, 256 threads (4 waves 2x2), XOR-swizzled LDS.
__global__ __launch_bounds__(256) void gemm_mfma(const u16* __restrict__ A3,
                                                 const u16* __restrict__ B3,
                                                 float* __restrict__ C,
                                                 int K3, int ldc, int Nreal) {
    __shared__ u16 As[128 * 64];
    __shared__ u16 Bs[64 * 64];
    int tid = threadIdx.x;
    int lane = tid & 63;
    int wave = tid >> 6;
    int wr = wave >> 1;
    int wc = wave & 1;
    int bm = blockIdx.y * 128;
    int bn = blockIdx.x * 64;

    f32x4 acc[4][2] = {};
    const size_t ldA = (size_t)K3 * 2;   // bytes per row

    for (int k0 = 0; k0 < K3; k0 += 64) {
        #pragma unroll
        for (int c = 0; c < 4; ++c) {
            int o = c * 4096 + tid * 16;
            int row = o >> 7;
            int slot = (o >> 4) & 7;
            int sslot = slot ^ (row & 7);
            const char* src = (const char*)A3 + (size_t)(bm + row) * ldA
                              + (size_t)k0 * 2 + sslot * 16;
            __builtin_amdgcn_global_load_lds(
                (const __attribute__((address_space(1))) u32*)src,
                (__attribute__((address_space(3))) u32*)((char*)As + o),
                16, 0, 0);
        }
        #pragma unroll
        for (int c = 0; c < 2; ++c) {
            int o = c * 4096 + tid * 16;
            int row = o >> 7;
            int slot = (o >> 4) & 7;
            int sslot = slot ^ (row & 7);
            const char* src = (const char*)B3 + (size_t)(bn + row) * ldA
                              + (size_t)k0 * 2 + sslot * 16;
            __builtin_amdgcn_global_load_lds(
                (const __attribute__((address_space(1))) u32*)src,
                (__attribute__((address_space(3))) u32*)((char*)Bs + o),
                16, 0, 0);
        }
        __syncthreads();
        #pragma unroll
        for (int kk = 0; kk < 2; ++kk) {
            int lslot = kk * 4 + (lane >> 4);
            short8 bfr[2];
            #pragma unroll
            for (int n = 0; n < 2; ++n) {
                int row = wc * 32 + n * 16 + (lane & 15);
                int pslot = lslot ^ (row & 7);
                bfr[n] = *(const short8*)((const char*)Bs + row * 128 + pslot * 16);
            }
            #pragma unroll
            for (int m = 0; m < 4; ++m) {
                int row = wr * 64 + m * 16 + (lane & 15);
                int pslot = lslot ^ (row & 7);
                short8 afr = *(const short8*)((const char*)As + row * 128 + pslot * 16);
                acc[m][0] = __builtin_amdgcn_mfma_f32_16x16x32_bf16(afr, bfr[0], acc[m][0], 0, 0, 0);
                acc[m][1] = __builtin_amdgcn_mfma_f32_16x16x32_bf16(afr, bfr[1], acc[m][1], 0, 0, 0);
            }
        }
        __syncthreads();
    }

    int crow0 = bm + wr * 64;
    int ccol0 = bn + wc * 32;
    #pragma unroll
    for (int m = 0; m < 4; ++m) {
        #pragma unroll
        for (int n = 0; n < 2; ++n) {
            int col = ccol0 + n * 16 + (lane & 15);
            if (col < Nreal) {
                #pragma unroll
                for (int j = 0; j < 4; ++j) {
                    int rrow = crow0 + m * 16 + (lane >> 4) * 4 + j;
                    C[(size_t)rrow * ldc + col] = acc[m][n][j];
                }
            }
        }
    }
}

// ---------------- encoder LN (wave/row): h += mb+em; LN; write h + A3 -------
__global__ __launch_bounds__(256) void enc_ln_k(float* __restrict__ h,
        const float* __restrict__ mb, const float* __restrict__ em,
        const float* __restrict__ w, const float* __restrict__ bb,
        u16* __restrict__ A3) {
    int row = blockIdx.x * 4 + (threadIdx.x >> 6);
    int lane = threadIdx.x & 63;
    int e = lane * 4;
    float* hr = h + (size_t)row * DM;
    f32x4 v = *(const f32x4*)(hr + e);
    f32x4 vm = *(const f32x4*)(mb + e);
    f32x4 ve = *(const f32x4*)(em + e);
    float s = 0.f, sq = 0.f;
    #pragma unroll
    for (int j = 0; j < 4; ++j) {
        v[j] += vm[j] + ve[j];
        s += v[j];
        sq += v[j] * v[j];
    }
    s = wave_sum(s); sq = wave_sum(sq);
    float mean = s * (1.f / DM);
    float var = sq * (1.f / DM) - mean * mean;
    float r = rsqrtf(var + 1e-5f);
    f32x4 vw = *(const f32x4*)(w + e);
    f32x4 vb = *(const f32x4*)(bb + e);
    f32x4 o;
    short4v hi4, lo4;
    #pragma unroll
    for (int j = 0; j < 4; ++j) {
        float ov = (v[j] - mean) * r * vw[j] + vb[j];
        o[j] = ov;
        u16 hi, lo; split_bf(ov, hi, lo);
        hi4[j] = (short)hi; lo4[j] = (short)lo;
    }
    *(f32x4*)(hr + e) = o;
    u16* ar = A3 + (size_t)row * 768;
    *(short4v*)(ar + e) = hi4;
    *(short4v*)(ar + 256 + e) = hi4;
    *(short4v*)(ar + 512 + e) = lo4;
}

// ---------------- dt = softplus(dt_raw + dt_bias) ---------------------------
__global__ void dt_k(const float* __restrict__ zx, const float* __restrict__ dtb_in,
                     float* __restrict__ dtb) {
    int idx = blockIdx.x * blockDim.x + threadIdx.x;
    if (idx >= M_TOT * NH) return;
    int hh = idx % NH;
    int m = idx / NH;
    float xv = zx[(size_t)m * DIP + (DI + CD) + hh] + dtb_in[hh];
    float sp = (xv > 20.f) ? xv : log1pf(expf(xv));
    dtb[idx] = sp;
}

// ---------------- causal depthwise conv (K=4) + silu on xBC -----------------
__global__ void conv_k(const float* __restrict__ zx, const float* __restrict__ cw,
                       const float* __restrict__ cb, float* __restrict__ xbc) {
    int idx = blockIdx.x * blockDim.x + threadIdx.x;
    if (idx >= M_TOT * CD) return;
    int c = idx % CD;
    int m = idx / CD;
    int t = m % T_;
    float acc = cb[c];
    #pragma unroll
    for (int k = 0; k < 4; ++k) {
        int tt = t - 3 + k;
        if (tt >= 0) acc += cw[c*4+k] * zx[(size_t)(m - (3 - k)) * DIP + DI + c];
    }
    float s = acc / (1.f + expf(-acc));
    xbc[idx] = s;
}

// ---------------- selective scan: block=(b,hquarter), thread=(h,p), s[n] regs
__global__ __launch_bounds__(128) void scan_k(const float* __restrict__ xbc,
        const float* __restrict__ dtb, const float* __restrict__ A_log,
        const float* __restrict__ D_skip, float* __restrict__ y) {
    int b  = blockIdx.x >> 2;
    int hq = blockIdx.x & 3;
    int h  = hq * 4 + (threadIdx.x >> 5);
    int p  = threadIdx.x & 31;
    float A  = -expf(A_log[h]);
    float Dh = D_skip[h];
    float s[16];
    #pragma unroll
    for (int n = 0; n < 16; ++n) s[n] = 0.f;
    int base = b * T_;
    // prefetch t=0
    const float* row = xbc + (size_t)base * CD;
    float dt = dtb[base * NH + h];
    float xh = row[h * HD + p];
    f32x4 Bv[4], Cv[4];
    #pragma unroll
    for (int q = 0; q < 4; ++q) {
        Bv[q] = *(const f32x4*)(row + DI + q * 4);
        Cv[q] = *(const f32x4*)(row + DI + DSZ + q * 4);
    }
    for (int t = 0; t < T_; ++t) {
        int m = base + t;
        int tn = (t + 1 < T_) ? t + 1 : t;
        const float* rown = xbc + (size_t)(base + tn) * CD;
        float dt_n = dtb[(base + tn) * NH + h];
        float xh_n = rown[h * HD + p];
        f32x4 Bn_[4], Cn_[4];
        #pragma unroll
        for (int q = 0; q < 4; ++q) {
            Bn_[q] = *(const f32x4*)(rown + DI + q * 4);
            Cn_[q] = *(const f32x4*)(rown + DI + DSZ + q * 4);
        }
        float dA = expf(dt * A);
        float dtx = dt * xh;
        float ya0 = 0.f, ya1 = 0.f, ya2 = 0.f, ya3 = 0.f;
        #pragma unroll
        for (int q = 0; q < 4; ++q) {
            #pragma unroll
            for (int j = 0; j < 4; ++j) {
                int n = q * 4 + j;
                s[n] = fmaf(dA, s[n], dtx * Bv[q][j]);
                float prod = s[n] * Cv[q][j];
                if (q == 0) ya0 += prod;
                else if (q == 1) ya1 += prod;
                else if (q == 2) ya2 += prod;
                else ya3 += prod;
            }
        }
        y[(size_t)m * DI + h * HD + p] = fmaf(Dh, xh, (ya0 + ya1) + (ya2 + ya3));
        dt = dt_n; xh = xh_n;
        #pragma unroll
        for (int q = 0; q < 4; ++q) { Bv[q] = Bn_[q]; Cv[q] = Cn_[q]; }
    }
}

// ---------------- gated RMSNorm (wave/row of 512) -> A3 (hi|hi|lo, K=512) ---
__global__ __launch_bounds__(256) void gate_rms_k(const float* __restrict__ y,
        const float* __restrict__ zx, const float* __restrict__ nw,
        u16* __restrict__ A3) {
    int row = blockIdx.x * 4 + (threadIdx.x >> 6);
    int lane = threadIdx.x & 63;
    int e0 = lane * 4, e1 = 256 + lane * 4;
    const float* yr = y + (size_t)row * DI;
    const float* zr = zx + (size_t)row * DIP;
    f32x4 y0 = *(const f32x4*)(yr + e0);
    f32x4 y1 = *(const f32x4*)(yr + e1);
    f32x4 z0 = *(const f32x4*)(zr + e0);
    f32x4 z1 = *(const f32x4*)(zr + e1);
    f32x4 g0, g1;
    float sq = 0.f;
    #pragma unroll
    for (int j = 0; j < 4; ++j) {
        g0[j] = y0[j] * (z0[j] / (1.f + expf(-z0[j])));
        g1[j] = y1[j] * (z1[j] / (1.f + expf(-z1[j])));
        sq += g0[j] * g0[j] + g1[j] * g1[j];
    }
    sq = wave_sum(sq);
    float r = rsqrtf(sq * (1.f / DI) + 1e-5f);
    f32x4 w0 = *(const f32x4*)(nw + e0);
    f32x4 w1 = *(const f32x4*)(nw + e1);
    u16* ar = A3 + (size_t)row * 1536;
    short4v hi4, lo4;
    #pragma unroll
    for (int j = 0; j < 4; ++j) {
        float ov = g0[j] * r * w0[j];
        u16 hi, lo; split_bf(ov, hi, lo);
        hi4[j] = (short)hi; lo4[j] = (short)lo;
    }
    *(short4v*)(ar + e0) = hi4;
    *(short4v*)(ar + 512 + e0) = hi4;
    *(short4v*)(ar + 1024 + e0) = lo4;
    #pragma unroll
    for (int j = 0; j < 4; ++j) {
        float ov = g1[j] * r * w1[j];
        u16 hi, lo; split_bf(ov, hi, lo);
        hi4[j] = (short)hi; lo4[j] = (short)lo;
    }
    *(short4v*)(ar + e1) = hi4;
    *(short4v*)(ar + 512 + e1) = hi4;
    *(short4v*)(ar + 1024 + e1) = lo4;
}

// ---------------- h = LN(c + h) (wave/row of 256) -> h + A3 (K=256) ---------
__global__ __launch_bounds__(256) void add_ln_k(float* __restrict__ h,
        const float* __restrict__ c, const float* __restrict__ w,
        const float* __restrict__ bb, u16* __restrict__ A3) {
    int row = blockIdx.x * 4 + (threadIdx.x >> 6);
    int lane = threadIdx.x & 63;
    int e = lane * 4;
    float* hr = h + (size_t)row * DM;
    const float* cr = c + (size_t)row * DM;
    f32x4 v = *(const f32x4*)(hr + e);
    f32x4 vc = *(const f32x4*)(cr + e);
    float s = 0.f, sq = 0.f;
    #pragma unroll
    for (int j = 0; j < 4; ++j) {
        v[j] += vc[j];
        s += v[j];
        sq += v[j] * v[j];
    }
    s = wave_sum(s); sq = wave_sum(sq);
    float mean = s * (1.f / DM);
    float var = sq * (1.f / DM) - mean * mean;
    float r = rsqrtf(var + 1e-5f);
    f32x4 vw = *(const f32x4*)(w + e);
    f32x4 vb = *(const f32x4*)(bb + e);
    f32x4 o;
    short4v hi4, lo4;
    #pragma unroll
    for (int j = 0; j < 4; ++j) {
        float ov = (v[j] - mean) * r * vw[j] + vb[j];
        o[j] = ov;
        u16 hi, lo; split_bf(ov, hi, lo);
        hi4[j] = (short)hi; lo4[j] = (short)lo;
    }
    *(f32x4*)(hr + e) = o;
    u16* ar = A3 + (size_t)row * 768;
    *(short4v*)(ar + e) = hi4;
    *(short4v*)(ar + 256 + e) = hi4;
    *(short4v*)(ar + 512 + e) = lo4;
}

// ---------------- mean over time -------------------------------------------
__global__ __launch_bounds__(DM) void pool_k(const float* __restrict__ h,
                                             float* __restrict__ pooled) {
    int b = blockIdx.x, d = threadIdx.x;
    float s = 0.f;
    for (int t = 0; t < T_; ++t) s += h[(size_t)(b * T_ + t) * DM + d];
    pooled[b * DM + d] = s * (1.f / T_);
}

// ---------------- head: relu(pooled@W1^T+b1)@W2^T + b2 ----------------------
__global__ __launch_bounds__(128) void head_k(const float* __restrict__ pooled,
        const float* __restrict__ w1, const float* __restrict__ b1,
        const float* __restrict__ w2, const float* __restrict__ b2,
        float* __restrict__ out) {
    int b = blockIdx.x, j = threadIdx.x;
    const float* pr = pooled + b * DM;
    float acc = b1[j];
    for (int d = 0; d < DM; ++d) acc += pr[d] * w1[j * DM + d];
    float hid = fmaxf(acc, 0.f);
    float v = hid * w2[j];
    #pragma unroll
    for (int off = 32; off > 0; off >>= 1) v += __shfl_xor(v, off);
    __shared__ float red[2];
    if ((j & 63) == 0) red[j >> 6] = v;
    __syncthreads();
    if (j == 0) out[b] = red[0] + red[1] + b2[0];
}

extern "C" void kernel_launch(void* const* d_in, const int* in_sizes, int n_in,
                              void* d_out, int out_size, void* d_ws, size_t ws_size,
                              hipStream_t stream) {
    const float* x         = (const float*)d_in[0];
    const float* emb       = (const float*)d_in[1];
    const float* sconv_w   = (const float*)d_in[2];
    const float* sconv_b   = (const float*)d_in[3];
    const float* mixer_w   = (const float*)d_in[4];
    const float* mixer_b   = (const float*)d_in[5];
    const float* enc_ln_w  = (const float*)d_in[6];
    const float* enc_ln_b  = (const float*)d_in[7];
    const float* in_proj_w = (const float*)d_in[8];
    const float* conv_w    = (const float*)d_in[9];
    const float* conv_b    = (const float*)d_in[10];
    const float* dt_bias   = (const float*)d_in[11];
    const float* A_log     = (const float*)d_in[12];
    const float* D_skip    = (const float*)d_in[13];
    const float* norm_w    = (const float*)d_in[14];
    const float* out_proj_w= (const float*)d_in[15];
    const float* ln_w      = (const float*)d_in[16];
    const float* ln_b      = (const float*)d_in[17];
    const float* head1_w   = (const float*)d_in[18];
    const float* head1_b   = (const float*)d_in[19];
    const float* head2_w   = (const float*)d_in[20];
    const float* head2_b   = (const float*)d_in[21];
    float* out = (float*)d_out;

    float* ws  = (float*)d_ws;
    float* h   = ws;                          // M*DM
    float* zx  = h   + (size_t)M_TOT * DM;    // M*DIP
    float* xbc = zx  + (size_t)M_TOT * DIP;   // M*CD
    float* dtb = xbc + (size_t)M_TOT * CD;    // M*NH
    float* y   = dtb + (size_t)M_TOT * NH;    // M*DI
    float* em  = y   + (size_t)M_TOT * DI;    // 256
    float* pooled = em + 256;                 // 16,384
    u16* A3 = (u16*)(pooled + 16384);         // 12800*1536 u16
    u16* B3 = A3 + (size_t)12800 * 1536;      // 1088*768 u16

    // ---- encoder ----
    emb_mean_k<<<1, DM, 0, stream>>>(emb, em);
    pack_b3_k<<<(DM * KENC + 255) / 256, 256, 0, stream>>>(mixer_w, B3, DM, DM, NCH_, KENC);
    xsA3_k<<<(M_TOT * KENC + 255) / 256, 256, 0, stream>>>(x, sconv_w, sconv_b, A3);
    gemm_mfma<<<dim3(4, 100), 256, 0, stream>>>(A3, B3, h, 3 * KENC, DM, DM);
    enc_ln_k<<<M_TOT / 4, 256, 0, stream>>>(h, mixer_b, em, enc_ln_w, enc_ln_b, A3);

    for (int l = 0; l < 4; ++l) {
        // in_proj: K=256 -> K3=768, N=1072 (pad 1088); A3 written by enc_ln/add_ln
        pack_b3_k<<<(1088 * DM + 255) / 256, 256, 0, stream>>>(
            in_proj_w + (size_t)l * DIP * DM, B3, DIP, 1088, DM, DM);
        gemm_mfma<<<dim3(17, 100), 256, 0, stream>>>(A3, B3, zx, 768, DIP, DIP);

        dt_k<<<(M_TOT * NH + 255) / 256, 256, 0, stream>>>(zx, dt_bias + l * NH, dtb);
        conv_k<<<(M_TOT * CD + 255) / 256, 256, 0, stream>>>(
            zx, conv_w + l * CD * 4, conv_b + l * CD, xbc);
        scan_k<<<B_ * 4, 128, 0, stream>>>(xbc, dtb, A_log + l * NH, D_skip + l * NH, y);
        gate_rms_k<<<M_TOT / 4, 256, 0, stream>>>(y, zx, norm_w + l * DI, A3);

        // out_proj: K=512 -> K3=1536, N=256
        pack_b3_k<<<(DM * DI + 255) / 256, 256, 0, stream>>>(
            out_proj_w + (size_t)l * DM * DI, B3, DM, DM, DI, DI);
        gemm_mfma<<<dim3(4, 100), 256, 0, stream>>>(A3, B3, zx, 1536, DM, DM);

        add_ln_k<<<M_TOT / 4, 256, 0, stream>>>(h, zx, ln_w + l * DM, ln_b + l * DM, A3);
    }

    pool_k<<<B_, DM, 0, stream>>>(h, pooled);
    head_k<<<B_, 128, 0, stream>>>(pooled, head1_w, head1_b, head2_w, head2_b, out);
}

// Round 4
// 812.363 us; speedup vs baseline: 2.7878x; 1.2290x over previous
//
#include <hip/hip_runtime.h>
#include <math.h>

#define B_   64
#define T_   200
#define DM   256
#define DI   512
#define NH   16
#define HD   32
#define DSZ  16
#define CD   544
#define DIP  1072
#define M_TOT (B_*T_)   // 12800
#define NCH_ 129
#define KENC 192        // encoder K padded (129 -> 192, 3*192 = 576 = 9*64)
#define NCHUNK 8
#define CLEN  25        // 200 / 8

typedef unsigned short u16;
typedef unsigned int u32;
typedef __attribute__((ext_vector_type(8))) short short8;   // 8 bf16
typedef __attribute__((ext_vector_type(4))) short short4v;  // 4 bf16
typedef __attribute__((ext_vector_type(4))) float f32x4;

// ---------------- helpers ----------------------------------------------------
__device__ __forceinline__ float wave_sum(float v) {
    #pragma unroll
    for (int off = 32; off > 0; off >>= 1) v += __shfl_xor(v, off);
    return v;
}
__device__ __forceinline__ u16 f2bf_rn(float f) {
    u32 u = __float_as_uint(f);
    u32 r = (u + 0x7fffu + ((u >> 16) & 1u)) >> 16;
    return (u16)r;
}
__device__ __forceinline__ float bf2f(u16 h) {
    return __uint_as_float(((u32)h) << 16);
}
__device__ __forceinline__ void split_bf(float a, u16& hi, u16& lo) {
    hi = f2bf_rn(a);
    lo = f2bf_rn(a - bf2f(hi));
}

// ---------------- emb mean over channels ------------------------------------
__global__ void emb_mean_k(const float* __restrict__ emb, float* __restrict__ em) {
    int d = threadIdx.x;
    float s = 0.f;
    for (int c = 0; c < NCH_; ++c) s += emb[c * DM + d];
    em[d] = s * (1.f / NCH_);
}

// ---------------- encoder dwconv (K=3) -> A3 [M x 3*KENC] (hi|hi|lo) --------
__global__ void xsA3_k(const float* __restrict__ x, const float* __restrict__ w,
                       const float* __restrict__ b, u16* __restrict__ A3) {
    int idx = blockIdx.x * blockDim.x + threadIdx.x;
    if (idx >= M_TOT * KENC) return;
    int c = idx % KENC;
    int m = idx / KENC;
    float acc = 0.f;
    if (c < NCH_) {
        int t = m % T_;
        int bb = m / T_;
        const float* xr = x + (size_t)(bb * NCH_ + c) * T_;
        acc = b[c];
        if (t > 0)      acc += w[c*3+0] * xr[t-1];
        acc += w[c*3+1] * xr[t];
        if (t < T_-1)   acc += w[c*3+2] * xr[t+1];
    }
    u16 hi, lo; split_bf(acc, hi, lo);
    u16* row = A3 + (size_t)m * (3*KENC);
    row[c] = hi; row[KENC + c] = hi; row[2*KENC + c] = lo;
}

// ---------------- pack weights fp32 -> bf16x3 [hi | lo | hi] ----------------
__global__ void pack_b3_k(const float* __restrict__ Bm, u16* __restrict__ B3,
                          int N, int Npad, int Kreal, int K) {
    int idx = blockIdx.x * blockDim.x + threadIdx.x;
    if (idx >= Npad * K) return;
    int k = idx % K, n = idx / K;
    u16 hi = 0, lo = 0;
    if (n < N && k < Kreal) {
        float b = Bm[(size_t)n * Kreal + k];
        split_bf(b, hi, lo);
    }
    u16* row = B3 + (size_t)n * 3 * K;
    row[k] = hi;
    row[K + k] = lo;
    row[2 * K + k] = hi;
}

// ---------------- MFMA bf16 GEMM: C[M,ldc](cols<Nreal) = A3[M,K3]*B3[.,K3]^T
__global__ __launch_bounds__(256) void gemm_mfma(const u16* __restrict__ A3,
                                                 const u16* __restrict__ B3,
                                                 float* __restrict__ C,
                                                 int K3, int ldc, int Nreal) {
    __shared__ u16 As[128 * 64];
    __shared__ u16 Bs[64 * 64];
    int tid = threadIdx.x;
    int lane = tid & 63;
    int wave = tid >> 6;
    int wr = wave >> 1;
    int wc = wave & 1;
    int bm = blockIdx.y * 128;
    int bn = blockIdx.x * 64;

    f32x4 acc[4][2] = {};
    const size_t ldA = (size_t)K3 * 2;   // bytes per row

    for (int k0 = 0; k0 < K3; k0 += 64) {
        #pragma unroll
        for (int c = 0; c < 4; ++c) {
            int o = c * 4096 + tid * 16;
            int row = o >> 7;
            int slot = (o >> 4) & 7;
            int sslot = slot ^ (row & 7);
            const char* src = (const char*)A3 + (size_t)(bm + row) * ldA
                              + (size_t)k0 * 2 + sslot * 16;
            __builtin_amdgcn_global_load_lds(
                (const __attribute__((address_space(1))) u32*)src,
                (__attribute__((address_space(3))) u32*)((char*)As + o),
                16, 0, 0);
        }
        #pragma unroll
        for (int c = 0; c < 2; ++c) {
            int o = c * 4096 + tid * 16;
            int row = o >> 7;
            int slot = (o >> 4) & 7;
            int sslot = slot ^ (row & 7);
            const char* src = (const char*)B3 + (size_t)(bn + row) * ldA
                              + (size_t)k0 * 2 + sslot * 16;
            __builtin_amdgcn_global_load_lds(
                (const __attribute__((address_space(1))) u32*)src,
                (__attribute__((address_space(3))) u32*)((char*)Bs + o),
                16, 0, 0);
        }
        __syncthreads();
        #pragma unroll
        for (int kk = 0; kk < 2; ++kk) {
            int lslot = kk * 4 + (lane >> 4);
            short8 bfr[2];
            #pragma unroll
            for (int n = 0; n < 2; ++n) {
                int row = wc * 32 + n * 16 + (lane & 15);
                int pslot = lslot ^ (row & 7);
                bfr[n] = *(const short8*)((const char*)Bs + row * 128 + pslot * 16);
            }
            #pragma unroll
            for (int m = 0; m < 4; ++m) {
                int row = wr * 64 + m * 16 + (lane & 15);
                int pslot = lslot ^ (row & 7);
                short8 afr = *(const short8*)((const char*)As + row * 128 + pslot * 16);
                acc[m][0] = __builtin_amdgcn_mfma_f32_16x16x32_bf16(afr, bfr[0], acc[m][0], 0, 0, 0);
                acc[m][1] = __builtin_amdgcn_mfma_f32_16x16x32_bf16(afr, bfr[1], acc[m][1], 0, 0, 0);
            }
        }
        __syncthreads();
    }

    int crow0 = bm + wr * 64;
    int ccol0 = bn + wc * 32;
    #pragma unroll
    for (int m = 0; m < 4; ++m) {
        #pragma unroll
        for (int n = 0; n < 2; ++n) {
            int col = ccol0 + n * 16 + (lane & 15);
            if (col < Nreal) {
                #pragma unroll
                for (int j = 0; j < 4; ++j) {
                    int rrow = crow0 + m * 16 + (lane >> 4) * 4 + j;
                    C[(size_t)rrow * ldc + col] = acc[m][n][j];
                }
            }
        }
    }
}

// ---------------- encoder LN (wave/row): h += mb+em; LN; write h + A3 -------
__global__ __launch_bounds__(256) void enc_ln_k(float* __restrict__ h,
        const float* __restrict__ mb, const float* __restrict__ em,
        const float* __restrict__ w, const float* __restrict__ bb,
        u16* __restrict__ A3) {
    int row = blockIdx.x * 4 + (threadIdx.x >> 6);
    int lane = threadIdx.x & 63;
    int e = lane * 4;
    float* hr = h + (size_t)row * DM;
    f32x4 v = *(const f32x4*)(hr + e);
    f32x4 vm = *(const f32x4*)(mb + e);
    f32x4 ve = *(const f32x4*)(em + e);
    float s = 0.f, sq = 0.f;
    #pragma unroll
    for (int j = 0; j < 4; ++j) {
        v[j] += vm[j] + ve[j];
        s += v[j];
        sq += v[j] * v[j];
    }
    s = wave_sum(s); sq = wave_sum(sq);
    float mean = s * (1.f / DM);
    float var = sq * (1.f / DM) - mean * mean;
    float r = rsqrtf(var + 1e-5f);
    f32x4 vw = *(const f32x4*)(w + e);
    f32x4 vb = *(const f32x4*)(bb + e);
    f32x4 o;
    short4v hi4, lo4;
    #pragma unroll
    for (int j = 0; j < 4; ++j) {
        float ov = (v[j] - mean) * r * vw[j] + vb[j];
        o[j] = ov;
        u16 hi, lo; split_bf(ov, hi, lo);
        hi4[j] = (short)hi; lo4[j] = (short)lo;
    }
    *(f32x4*)(hr + e) = o;
    u16* ar = A3 + (size_t)row * 768;
    *(short4v*)(ar + e) = hi4;
    *(short4v*)(ar + 256 + e) = hi4;
    *(short4v*)(ar + 512 + e) = lo4;
}

// ---------------- dt = softplus(dt_raw + dt_bias) ---------------------------
__global__ void dt_k(const float* __restrict__ zx, const float* __restrict__ dtb_in,
                     float* __restrict__ dtb) {
    int idx = blockIdx.x * blockDim.x + threadIdx.x;
    if (idx >= M_TOT * NH) return;
    int hh = idx % NH;
    int m = idx / NH;
    float xv = zx[(size_t)m * DIP + (DI + CD) + hh] + dtb_in[hh];
    float sp = (xv > 20.f) ? xv : log1pf(expf(xv));
    dtb[idx] = sp;
}

// ---------------- causal depthwise conv (K=4) + silu on xBC -----------------
__global__ void conv_k(const float* __restrict__ zx, const float* __restrict__ cw,
                       const float* __restrict__ cb, float* __restrict__ xbc) {
    int idx = blockIdx.x * blockDim.x + threadIdx.x;
    if (idx >= M_TOT * CD) return;
    int c = idx % CD;
    int m = idx / CD;
    int t = m % T_;
    float acc = cb[c];
    #pragma unroll
    for (int k = 0; k < 4; ++k) {
        int tt = t - 3 + k;
        if (tt >= 0) acc += cw[c*4+k] * zx[(size_t)(m - (3 - k)) * DIP + DI + c];
    }
    float s = acc / (1.f + expf(-acc));
    xbc[idx] = s;
}

// ---------------- scan pass 1: chunk-local scan -----------------------------
// block = (b, hq, chunk): 64*4*8 = 2048 blocks, 128 thr (h=hq*4+tid>>5, p=tid&31)
__global__ __launch_bounds__(128) void scan1_k(const float* __restrict__ xbc,
        const float* __restrict__ dtb, const float* __restrict__ A_log,
        const float* __restrict__ D_skip, float* __restrict__ y,
        float* __restrict__ s_end, float* __restrict__ Pprod) {
    int c   = blockIdx.x & 7;
    int bhq = blockIdx.x >> 3;
    int b   = bhq >> 2;
    int hq  = bhq & 3;
    int h   = hq * 4 + (threadIdx.x >> 5);
    int p   = threadIdx.x & 31;
    float A  = -expf(A_log[h]);
    float Dh = D_skip[h];
    float s[16];
    #pragma unroll
    for (int n = 0; n < 16; ++n) s[n] = 0.f;
    float pr = 1.f;
    int base = b * T_ + c * CLEN;
    const float* row = xbc + (size_t)base * CD;
    float dt = dtb[base * NH + h];
    float xh = row[h * HD + p];
    f32x4 Bv[4], Cv[4];
    #pragma unroll
    for (int q = 0; q < 4; ++q) {
        Bv[q] = *(const f32x4*)(row + DI + q * 4);
        Cv[q] = *(const f32x4*)(row + DI + DSZ + q * 4);
    }
    for (int t = 0; t < CLEN; ++t) {
        int m = base + t;
        int tn = (t + 1 < CLEN) ? t + 1 : t;
        const float* rown = xbc + (size_t)(base + tn) * CD;
        float dt_n = dtb[(base + tn) * NH + h];
        float xh_n = rown[h * HD + p];
        f32x4 Bn_[4], Cn_[4];
        #pragma unroll
        for (int q = 0; q < 4; ++q) {
            Bn_[q] = *(const f32x4*)(rown + DI + q * 4);
            Cn_[q] = *(const f32x4*)(rown + DI + DSZ + q * 4);
        }
        float dA = expf(dt * A);
        pr *= dA;
        float dtx = dt * xh;
        float ya0 = 0.f, ya1 = 0.f, ya2 = 0.f, ya3 = 0.f;
        #pragma unroll
        for (int q = 0; q < 4; ++q) {
            #pragma unroll
            for (int j = 0; j < 4; ++j) {
                int n = q * 4 + j;
                s[n] = fmaf(dA, s[n], dtx * Bv[q][j]);
                float prod = s[n] * Cv[q][j];
                if (q == 0) ya0 += prod;
                else if (q == 1) ya1 += prod;
                else if (q == 2) ya2 += prod;
                else ya3 += prod;
            }
        }
        y[(size_t)m * DI + h * HD + p] = fmaf(Dh, xh, (ya0 + ya1) + (ya2 + ya3));
        dt = dt_n; xh = xh_n;
        #pragma unroll
        for (int q = 0; q < 4; ++q) { Bv[q] = Bn_[q]; Cv[q] = Cn_[q]; }
    }
    size_t sidx = ((((size_t)b * NH + h) * NCHUNK + c) * 32 + p) * 16;
    #pragma unroll
    for (int q = 0; q < 4; ++q) {
        f32x4 v; v[0]=s[q*4]; v[1]=s[q*4+1]; v[2]=s[q*4+2]; v[3]=s[q*4+3];
        *(f32x4*)(s_end + sidx + q * 4) = v;
    }
    if (p == 0) Pprod[(b * NH + h) * NCHUNK + c] = pr;
}

// ---------------- scan pass 2: combine chunk states (sequential over 8) -----
// block = (b, hq): 256 blocks x 128 thr
__global__ __launch_bounds__(128) void scan2_k(const float* __restrict__ s_end,
        const float* __restrict__ Pprod, float* __restrict__ s_init) {
    int b  = blockIdx.x >> 2;
    int hq = blockIdx.x & 3;
    int h  = hq * 4 + (threadIdx.x >> 5);
    int p  = threadIdx.x & 31;
    float s[16];
    #pragma unroll
    for (int n = 0; n < 16; ++n) s[n] = 0.f;
    size_t bh = (size_t)b * NH + h;
    for (int c = 1; c < NCHUNK; ++c) {
        float P = Pprod[bh * NCHUNK + (c - 1)];
        size_t eidx = ((bh * NCHUNK + (c - 1)) * 32 + p) * 16;
        size_t iidx = ((bh * NCHUNK + c) * 32 + p) * 16;
        #pragma unroll
        for (int q = 0; q < 4; ++q) {
            f32x4 e = *(const f32x4*)(s_end + eidx + q * 4);
            f32x4 o;
            #pragma unroll
            for (int j = 0; j < 4; ++j) {
                s[q*4+j] = fmaf(P, s[q*4+j], e[j]);
                o[j] = s[q*4+j];
            }
            *(f32x4*)(s_init + iidx + q * 4) = o;
        }
    }
}

// ---------------- scan pass 3: y += cumdA * (C . s_init) for chunks 1..7 ----
// block = (b, hq, c-1): 64*4*7 = 1792 blocks x 128 thr
__global__ __launch_bounds__(128) void scan3_k(const float* __restrict__ xbc,
        const float* __restrict__ dtb, const float* __restrict__ A_log,
        const float* __restrict__ s_init, float* __restrict__ y) {
    int c   = (blockIdx.x % 7) + 1;
    int bhq = blockIdx.x / 7;
    int b   = bhq >> 2;
    int hq  = bhq & 3;
    int h   = hq * 4 + (threadIdx.x >> 5);
    int p   = threadIdx.x & 31;
    float A = -expf(A_log[h]);
    size_t iidx = ((((size_t)b * NH + h) * NCHUNK + c) * 32 + p) * 16;
    float si[16];
    #pragma unroll
    for (int q = 0; q < 4; ++q) {
        f32x4 v = *(const f32x4*)(s_init + iidx + q * 4);
        si[q*4] = v[0]; si[q*4+1] = v[1]; si[q*4+2] = v[2]; si[q*4+3] = v[3];
    }
    float cum = 1.f;
    int base = b * T_ + c * CLEN;
    for (int t = 0; t < CLEN; ++t) {
        int m = base + t;
        float dt = dtb[m * NH + h];
        cum *= expf(dt * A);
        const float* Cr = xbc + (size_t)m * CD + DI + DSZ;
        float dot = 0.f;
        #pragma unroll
        for (int q = 0; q < 4; ++q) {
            f32x4 Cv = *(const f32x4*)(Cr + q * 4);
            #pragma unroll
            for (int j = 0; j < 4; ++j) dot = fmaf(si[q*4+j], Cv[j], dot);
        }
        y[(size_t)m * DI + h * HD + p] += cum * dot;
    }
}

// ---------------- gated RMSNorm (wave/row of 512) -> A3 (hi|hi|lo, K=512) ---
__global__ __launch_bounds__(256) void gate_rms_k(const float* __restrict__ y,
        const float* __restrict__ zx, const float* __restrict__ nw,
        u16* __restrict__ A3) {
    int row = blockIdx.x * 4 + (threadIdx.x >> 6);
    int lane = threadIdx.x & 63;
    int e0 = lane * 4, e1 = 256 + lane * 4;
    const float* yr = y + (size_t)row * DI;
    const float* zr = zx + (size_t)row * DIP;
    f32x4 y0 = *(const f32x4*)(yr + e0);
    f32x4 y1 = *(const f32x4*)(yr + e1);
    f32x4 z0 = *(const f32x4*)(zr + e0);
    f32x4 z1 = *(const f32x4*)(zr + e1);
    f32x4 g0, g1;
    float sq = 0.f;
    #pragma unroll
    for (int j = 0; j < 4; ++j) {
        g0[j] = y0[j] * (z0[j] / (1.f + expf(-z0[j])));
        g1[j] = y1[j] * (z1[j] / (1.f + expf(-z1[j])));
        sq += g0[j] * g0[j] + g1[j] * g1[j];
    }
    sq = wave_sum(sq);
    float r = rsqrtf(sq * (1.f / DI) + 1e-5f);
    f32x4 w0 = *(const f32x4*)(nw + e0);
    f32x4 w1 = *(const f32x4*)(nw + e1);
    u16* ar = A3 + (size_t)row * 1536;
    short4v hi4, lo4;
    #pragma unroll
    for (int j = 0; j < 4; ++j) {
        float ov = g0[j] * r * w0[j];
        u16 hi, lo; split_bf(ov, hi, lo);
        hi4[j] = (short)hi; lo4[j] = (short)lo;
    }
    *(short4v*)(ar + e0) = hi4;
    *(short4v*)(ar + 512 + e0) = hi4;
    *(short4v*)(ar + 1024 + e0) = lo4;
    #pragma unroll
    for (int j = 0; j < 4; ++j) {
        float ov = g1[j] * r * w1[j];
        u16 hi, lo; split_bf(ov, hi, lo);
        hi4[j] = (short)hi; lo4[j] = (short)lo;
    }
    *(short4v*)(ar + e1) = hi4;
    *(short4v*)(ar + 512 + e1) = hi4;
    *(short4v*)(ar + 1024 + e1) = lo4;
}

// ---------------- h = LN(c + h) (wave/row of 256) -> h + A3 (K=256) ---------
__global__ __launch_bounds__(256) void add_ln_k(float* __restrict__ h,
        const float* __restrict__ c, const float* __restrict__ w,
        const float* __restrict__ bb, u16* __restrict__ A3) {
    int row = blockIdx.x * 4 + (threadIdx.x >> 6);
    int lane = threadIdx.x & 63;
    int e = lane * 4;
    float* hr = h + (size_t)row * DM;
    const float* cr = c + (size_t)row * DM;
    f32x4 v = *(const f32x4*)(hr + e);
    f32x4 vc = *(const f32x4*)(cr + e);
    float s = 0.f, sq = 0.f;
    #pragma unroll
    for (int j = 0; j < 4; ++j) {
        v[j] += vc[j];
        s += v[j];
        sq += v[j] * v[j];
    }
    s = wave_sum(s); sq = wave_sum(sq);
    float mean = s * (1.f / DM);
    float var = sq * (1.f / DM) - mean * mean;
    float r = rsqrtf(var + 1e-5f);
    f32x4 vw = *(const f32x4*)(w + e);
    f32x4 vb = *(const f32x4*)(bb + e);
    f32x4 o;
    short4v hi4, lo4;
    #pragma unroll
    for (int j = 0; j < 4; ++j) {
        float ov = (v[j] - mean) * r * vw[j] + vb[j];
        o[j] = ov;
        u16 hi, lo; split_bf(ov, hi, lo);
        hi4[j] = (short)hi; lo4[j] = (short)lo;
    }
    *(f32x4*)(hr + e) = o;
    u16* ar = A3 + (size_t)row * 768;
    *(short4v*)(ar + e) = hi4;
    *(short4v*)(ar + 256 + e) = hi4;
    *(short4v*)(ar + 512 + e) = lo4;
}

// ---------------- mean over time -------------------------------------------
__global__ __launch_bounds__(DM) void pool_k(const float* __restrict__ h,
                                             float* __restrict__ pooled) {
    int b = blockIdx.x, d = threadIdx.x;
    float s = 0.f;
    for (int t = 0; t < T_; ++t) s += h[(size_t)(b * T_ + t) * DM + d];
    pooled[b * DM + d] = s * (1.f / T_);
}

// ---------------- head: relu(pooled@W1^T+b1)@W2^T + b2 ----------------------
__global__ __launch_bounds__(128) void head_k(const float* __restrict__ pooled,
        const float* __restrict__ w1, const float* __restrict__ b1,
        const float* __restrict__ w2, const float* __restrict__ b2,
        float* __restrict__ out) {
    int b = blockIdx.x, j = threadIdx.x;
    const float* pr = pooled + b * DM;
    float acc = b1[j];
    for (int d = 0; d < DM; ++d) acc += pr[d] * w1[j * DM + d];
    float hid = fmaxf(acc, 0.f);
    float v = hid * w2[j];
    #pragma unroll
    for (int off = 32; off > 0; off >>= 1) v += __shfl_xor(v, off);
    __shared__ float red[2];
    if ((j & 63) == 0) red[j >> 6] = v;
    __syncthreads();
    if (j == 0) out[b] = red[0] + red[1] + b2[0];
}

extern "C" void kernel_launch(void* const* d_in, const int* in_sizes, int n_in,
                              void* d_out, int out_size, void* d_ws, size_t ws_size,
                              hipStream_t stream) {
    const float* x         = (const float*)d_in[0];
    const float* emb       = (const float*)d_in[1];
    const float* sconv_w   = (const float*)d_in[2];
    const float* sconv_b   = (const float*)d_in[3];
    const float* mixer_w   = (const float*)d_in[4];
    const float* mixer_b   = (const float*)d_in[5];
    const float* enc_ln_w  = (const float*)d_in[6];
    const float* enc_ln_b  = (const float*)d_in[7];
    const float* in_proj_w = (const float*)d_in[8];
    const float* conv_w    = (const float*)d_in[9];
    const float* conv_b    = (const float*)d_in[10];
    const float* dt_bias   = (const float*)d_in[11];
    const float* A_log     = (const float*)d_in[12];
    const float* D_skip    = (const float*)d_in[13];
    const float* norm_w    = (const float*)d_in[14];
    const float* out_proj_w= (const float*)d_in[15];
    const float* ln_w      = (const float*)d_in[16];
    const float* ln_b      = (const float*)d_in[17];
    const float* head1_w   = (const float*)d_in[18];
    const float* head1_b   = (const float*)d_in[19];
    const float* head2_w   = (const float*)d_in[20];
    const float* head2_b   = (const float*)d_in[21];
    float* out = (float*)d_out;

    float* ws  = (float*)d_ws;
    float* h   = ws;                          // M*DM
    float* zx  = h   + (size_t)M_TOT * DM;    // M*DIP
    float* xbc = zx  + (size_t)M_TOT * DIP;   // M*CD
    float* dtb = xbc + (size_t)M_TOT * CD;    // M*NH
    float* y   = dtb + (size_t)M_TOT * NH;    // M*DI
    float* em  = y   + (size_t)M_TOT * DI;    // 256
    float* pooled = em + 256;                 // 16,384
    u16* A3 = (u16*)(pooled + 16384);         // 12800*1536 u16
    u16* B3 = A3 + (size_t)12800 * 1536;      // 1088*768 u16

    // scan scratch aliases A3 (A3 dead during scan; rewritten by gate_rms)
    float* s_end  = (float*)A3;                       // 64*16*8*512 floats
    float* s_init = s_end + (size_t)B_*NH*NCHUNK*512; // same size
    float* Pprod  = s_init + (size_t)B_*NH*NCHUNK*512;// 8192 floats

    // ---- encoder ----
    emb_mean_k<<<1, DM, 0, stream>>>(emb, em);
    pack_b3_k<<<(DM * KENC + 255) / 256, 256, 0, stream>>>(mixer_w, B3, DM, DM, NCH_, KENC);
    xsA3_k<<<(M_TOT * KENC + 255) / 256, 256, 0, stream>>>(x, sconv_w, sconv_b, A3);
    gemm_mfma<<<dim3(4, 100), 256, 0, stream>>>(A3, B3, h, 3 * KENC, DM, DM);
    enc_ln_k<<<M_TOT / 4, 256, 0, stream>>>(h, mixer_b, em, enc_ln_w, enc_ln_b, A3);

    for (int l = 0; l < 4; ++l) {
        // in_proj: K=256 -> K3=768, N=1072 (pad 1088); A3 written by enc_ln/add_ln
        pack_b3_k<<<(1088 * DM + 255) / 256, 256, 0, stream>>>(
            in_proj_w + (size_t)l * DIP * DM, B3, DIP, 1088, DM, DM);
        gemm_mfma<<<dim3(17, 100), 256, 0, stream>>>(A3, B3, zx, 768, DIP, DIP);

        dt_k<<<(M_TOT * NH + 255) / 256, 256, 0, stream>>>(zx, dt_bias + l * NH, dtb);
        conv_k<<<(M_TOT * CD + 255) / 256, 256, 0, stream>>>(
            zx, conv_w + l * CD * 4, conv_b + l * CD, xbc);

        scan1_k<<<B_ * 4 * NCHUNK, 128, 0, stream>>>(
            xbc, dtb, A_log + l * NH, D_skip + l * NH, y, s_end, Pprod);
        scan2_k<<<B_ * 4, 128, 0, stream>>>(s_end, Pprod, s_init);
        scan3_k<<<B_ * 4 * (NCHUNK - 1), 128, 0, stream>>>(
            xbc, dtb, A_log + l * NH, s_init, y);

        gate_rms_k<<<M_TOT / 4, 256, 0, stream>>>(y, zx, norm_w + l * DI, A3);

        // out_proj: K=512 -> K3=1536, N=256
        pack_b3_k<<<(DM * DI + 255) / 256, 256, 0, stream>>>(
            out_proj_w + (size_t)l * DM * DI, B3, DM, DM, DI, DI);
        gemm_mfma<<<dim3(4, 100), 256, 0, stream>>>(A3, B3, zx, 1536, DM, DM);

        add_ln_k<<<M_TOT / 4, 256, 0, stream>>>(h, zx, ln_w + l * DM, ln_b + l * DM, A3);
    }

    pool_k<<<B_, DM, 0, stream>>>(h, pooled);
    head_k<<<B_, 128, 0, stream>>>(pooled, head1_w, head1_b, head2_w, head2_b, out);
}

// Round 5
// 800.101 us; speedup vs baseline: 2.8305x; 1.0153x over previous
//
#include <hip/hip_runtime.h>
#include <math.h>

#define B_   64
#define T_   200
#define DM   256
#define DI   512
#define NH   16
#define HD   32
#define DSZ  16
#define CD   544
#define DIP  1072
#define M_TOT (B_*T_)   // 12800
#define NCH_ 129
#define KENC 192        // encoder K padded (129 -> 192, 3*192 = 576 = 9*64)
#define NCHUNK 8
#define CLEN  25        // 200 / 8

typedef unsigned short u16;
typedef unsigned int u32;
typedef __attribute__((ext_vector_type(8))) short short8;   // 8 bf16
typedef __attribute__((ext_vector_type(4))) short short4v;  // 4 bf16
typedef __attribute__((ext_vector_type(4))) float f32x4;

// ---------------- helpers ----------------------------------------------------
__device__ __forceinline__ float wave_sum(float v) {
    #pragma unroll
    for (int off = 32; off > 0; off >>= 1) v += __shfl_xor(v, off);
    return v;
}
__device__ __forceinline__ u16 f2bf_rn(float f) {
    u32 u = __float_as_uint(f);
    u32 r = (u + 0x7fffu + ((u >> 16) & 1u)) >> 16;
    return (u16)r;
}
__device__ __forceinline__ float bf2f(u16 h) {
    return __uint_as_float(((u32)h) << 16);
}
__device__ __forceinline__ void split_bf(float a, u16& hi, u16& lo) {
    hi = f2bf_rn(a);
    lo = f2bf_rn(a - bf2f(hi));
}

// ---------------- emb mean over channels ------------------------------------
__global__ void emb_mean_k(const float* __restrict__ emb, float* __restrict__ em) {
    int d = threadIdx.x;
    float s = 0.f;
    for (int c = 0; c < NCH_; ++c) s += emb[c * DM + d];
    em[d] = s * (1.f / NCH_);
}

// ---------------- encoder dwconv (K=3) -> A3 [M x 3*KENC] (hi|hi|lo) --------
__global__ void xsA3_k(const float* __restrict__ x, const float* __restrict__ w,
                       const float* __restrict__ b, u16* __restrict__ A3) {
    int idx = blockIdx.x * blockDim.x + threadIdx.x;
    if (idx >= M_TOT * KENC) return;
    int c = idx % KENC;
    int m = idx / KENC;
    float acc = 0.f;
    if (c < NCH_) {
        int t = m % T_;
        int bb = m / T_;
        const float* xr = x + (size_t)(bb * NCH_ + c) * T_;
        acc = b[c];
        if (t > 0)      acc += w[c*3+0] * xr[t-1];
        acc += w[c*3+1] * xr[t];
        if (t < T_-1)   acc += w[c*3+2] * xr[t+1];
    }
    u16 hi, lo; split_bf(acc, hi, lo);
    u16* row = A3 + (size_t)m * (3*KENC);
    row[c] = hi; row[KENC + c] = hi; row[2*KENC + c] = lo;
}

// ---------------- pack weights fp32 -> bf16x3 [hi | lo | hi] ----------------
__global__ void pack_b3_k(const float* __restrict__ Bm, u16* __restrict__ B3,
                          int N, int Npad, int Kreal, int K) {
    int idx = blockIdx.x * blockDim.x + threadIdx.x;
    if (idx >= Npad * K) return;
    int k = idx % K, n = idx / K;
    u16 hi = 0, lo = 0;
    if (n < N && k < Kreal) {
        float b = Bm[(size_t)n * Kreal + k];
        split_bf(b, hi, lo);
    }
    u16* row = B3 + (size_t)n * 3 * K;
    row[k] = hi;
    row[K + k] = lo;
    row[2 * K + k] = hi;
}

// ---------------- MFMA bf16 GEMM: C = A3 * B3^T, 128x128 tile, XCD swizzle --
// grid: 1D nbx*nby blocks, 256 thr (4 waves 2x2, each wave 64x64 output)
__global__ __launch_bounds__(256) void gemm_mfma(const u16* __restrict__ A3,
                                                 const u16* __restrict__ B3,
                                                 float* __restrict__ C,
                                                 int K3, int ldc, int Nreal,
                                                 int nbx) {
    __shared__ u16 As[128 * 64];
    __shared__ u16 Bs[128 * 64];
    // bijective XCD-chunked swizzle (m204)
    int nwg = gridDim.x;
    int lin = blockIdx.x;
    int q = nwg >> 3, r = nwg & 7;
    int xcd = lin & 7, idx = lin >> 3;
    int wg = ((xcd < r) ? xcd * (q + 1) : r * (q + 1) + (xcd - r) * q) + idx;
    int bx = wg % nbx, by = wg / nbx;

    int tid = threadIdx.x;
    int lane = tid & 63;
    int wave = tid >> 6;
    int wr = wave >> 1;
    int wc = wave & 1;
    int bm = by * 128;
    int bn = bx * 128;

    f32x4 acc[4][4] = {};
    const size_t ldA = (size_t)K3 * 2;   // bytes per row

    for (int k0 = 0; k0 < K3; k0 += 64) {
        #pragma unroll
        for (int c = 0; c < 4; ++c) {
            int o = c * 4096 + tid * 16;
            int row = o >> 7;
            int slot = (o >> 4) & 7;
            int sslot = slot ^ (row & 7);
            const char* src = (const char*)A3 + (size_t)(bm + row) * ldA
                              + (size_t)k0 * 2 + sslot * 16;
            __builtin_amdgcn_global_load_lds(
                (const __attribute__((address_space(1))) u32*)src,
                (__attribute__((address_space(3))) u32*)((char*)As + o),
                16, 0, 0);
        }
        #pragma unroll
        for (int c = 0; c < 4; ++c) {
            int o = c * 4096 + tid * 16;
            int row = o >> 7;
            int slot = (o >> 4) & 7;
            int sslot = slot ^ (row & 7);
            const char* src = (const char*)B3 + (size_t)(bn + row) * ldA
                              + (size_t)k0 * 2 + sslot * 16;
            __builtin_amdgcn_global_load_lds(
                (const __attribute__((address_space(1))) u32*)src,
                (__attribute__((address_space(3))) u32*)((char*)Bs + o),
                16, 0, 0);
        }
        __syncthreads();
        #pragma unroll
        for (int kk = 0; kk < 2; ++kk) {
            int lslot = kk * 4 + (lane >> 4);
            short8 afr[4], bfr[4];
            #pragma unroll
            for (int n = 0; n < 4; ++n) {
                int row = wc * 64 + n * 16 + (lane & 15);
                int pslot = lslot ^ (row & 7);
                bfr[n] = *(const short8*)((const char*)Bs + row * 128 + pslot * 16);
            }
            #pragma unroll
            for (int m = 0; m < 4; ++m) {
                int row = wr * 64 + m * 16 + (lane & 15);
                int pslot = lslot ^ (row & 7);
                afr[m] = *(const short8*)((const char*)As + row * 128 + pslot * 16);
            }
            #pragma unroll
            for (int m = 0; m < 4; ++m)
                #pragma unroll
                for (int n = 0; n < 4; ++n)
                    acc[m][n] = __builtin_amdgcn_mfma_f32_16x16x32_bf16(
                        afr[m], bfr[n], acc[m][n], 0, 0, 0);
        }
        __syncthreads();
    }

    int crow0 = bm + wr * 64;
    int ccol0 = bn + wc * 64;
    #pragma unroll
    for (int m = 0; m < 4; ++m) {
        #pragma unroll
        for (int n = 0; n < 4; ++n) {
            int col = ccol0 + n * 16 + (lane & 15);
            if (col < Nreal) {
                #pragma unroll
                for (int j = 0; j < 4; ++j) {
                    int rrow = crow0 + m * 16 + (lane >> 4) * 4 + j;
                    C[(size_t)rrow * ldc + col] = acc[m][n][j];
                }
            }
        }
    }
}

// ---------------- encoder LN (wave/row): h += mb+em; LN; write h + A3 -------
__global__ __launch_bounds__(256) void enc_ln_k(float* __restrict__ h,
        const float* __restrict__ mb, const float* __restrict__ em,
        const float* __restrict__ w, const float* __restrict__ bb,
        u16* __restrict__ A3) {
    int row = blockIdx.x * 4 + (threadIdx.x >> 6);
    int lane = threadIdx.x & 63;
    int e = lane * 4;
    float* hr = h + (size_t)row * DM;
    f32x4 v = *(const f32x4*)(hr + e);
    f32x4 vm = *(const f32x4*)(mb + e);
    f32x4 ve = *(const f32x4*)(em + e);
    float s = 0.f, sq = 0.f;
    #pragma unroll
    for (int j = 0; j < 4; ++j) {
        v[j] += vm[j] + ve[j];
        s += v[j];
        sq += v[j] * v[j];
    }
    s = wave_sum(s); sq = wave_sum(sq);
    float mean = s * (1.f / DM);
    float var = sq * (1.f / DM) - mean * mean;
    float r = rsqrtf(var + 1e-5f);
    f32x4 vw = *(const f32x4*)(w + e);
    f32x4 vb = *(const f32x4*)(bb + e);
    f32x4 o;
    short4v hi4, lo4;
    #pragma unroll
    for (int j = 0; j < 4; ++j) {
        float ov = (v[j] - mean) * r * vw[j] + vb[j];
        o[j] = ov;
        u16 hi, lo; split_bf(ov, hi, lo);
        hi4[j] = (short)hi; lo4[j] = (short)lo;
    }
    *(f32x4*)(hr + e) = o;
    u16* ar = A3 + (size_t)row * 768;
    *(short4v*)(ar + e) = hi4;
    *(short4v*)(ar + 256 + e) = hi4;
    *(short4v*)(ar + 512 + e) = lo4;
}

// ---------------- dt = softplus(dt_raw + dt_bias) ---------------------------
__global__ void dt_k(const float* __restrict__ zx, const float* __restrict__ dtb_in,
                     float* __restrict__ dtb) {
    int idx = blockIdx.x * blockDim.x + threadIdx.x;
    if (idx >= M_TOT * NH) return;
    int hh = idx % NH;
    int m = idx / NH;
    float xv = zx[(size_t)m * DIP + (DI + CD) + hh] + dtb_in[hh];
    float sp = (xv > 20.f) ? xv : log1pf(expf(xv));
    dtb[idx] = sp;
}

// ---------------- causal depthwise conv (K=4) + silu on xBC -----------------
__global__ void conv_k(const float* __restrict__ zx, const float* __restrict__ cw,
                       const float* __restrict__ cb, float* __restrict__ xbc) {
    int idx = blockIdx.x * blockDim.x + threadIdx.x;
    if (idx >= M_TOT * CD) return;
    int c = idx % CD;
    int m = idx / CD;
    int t = m % T_;
    float acc = cb[c];
    #pragma unroll
    for (int k = 0; k < 4; ++k) {
        int tt = t - 3 + k;
        if (tt >= 0) acc += cw[c*4+k] * zx[(size_t)(m - (3 - k)) * DIP + DI + c];
    }
    float s = acc / (1.f + expf(-acc));
    xbc[idx] = s;
}

// ---------------- scan pass 1: chunk-local scan -----------------------------
__global__ __launch_bounds__(128) void scan1_k(const float* __restrict__ xbc,
        const float* __restrict__ dtb, const float* __restrict__ A_log,
        const float* __restrict__ D_skip, float* __restrict__ y,
        float* __restrict__ s_end, float* __restrict__ Pprod) {
    int c   = blockIdx.x & 7;
    int bhq = blockIdx.x >> 3;
    int b   = bhq >> 2;
    int hq  = bhq & 3;
    int h   = hq * 4 + (threadIdx.x >> 5);
    int p   = threadIdx.x & 31;
    float A  = -expf(A_log[h]);
    float Dh = D_skip[h];
    float s[16];
    #pragma unroll
    for (int n = 0; n < 16; ++n) s[n] = 0.f;
    float pr = 1.f;
    int base = b * T_ + c * CLEN;
    const float* row = xbc + (size_t)base * CD;
    float dt = dtb[base * NH + h];
    float xh = row[h * HD + p];
    f32x4 Bv[4], Cv[4];
    #pragma unroll
    for (int q = 0; q < 4; ++q) {
        Bv[q] = *(const f32x4*)(row + DI + q * 4);
        Cv[q] = *(const f32x4*)(row + DI + DSZ + q * 4);
    }
    for (int t = 0; t < CLEN; ++t) {
        int m = base + t;
        int tn = (t + 1 < CLEN) ? t + 1 : t;
        const float* rown = xbc + (size_t)(base + tn) * CD;
        float dt_n = dtb[(base + tn) * NH + h];
        float xh_n = rown[h * HD + p];
        f32x4 Bn_[4], Cn_[4];
        #pragma unroll
        for (int q = 0; q < 4; ++q) {
            Bn_[q] = *(const f32x4*)(rown + DI + q * 4);
            Cn_[q] = *(const f32x4*)(rown + DI + DSZ + q * 4);
        }
        float dA = expf(dt * A);
        pr *= dA;
        float dtx = dt * xh;
        float ya0 = 0.f, ya1 = 0.f, ya2 = 0.f, ya3 = 0.f;
        #pragma unroll
        for (int q = 0; q < 4; ++q) {
            #pragma unroll
            for (int j = 0; j < 4; ++j) {
                int n = q * 4 + j;
                s[n] = fmaf(dA, s[n], dtx * Bv[q][j]);
                float prod = s[n] * Cv[q][j];
                if (q == 0) ya0 += prod;
                else if (q == 1) ya1 += prod;
                else if (q == 2) ya2 += prod;
                else ya3 += prod;
            }
        }
        y[(size_t)m * DI + h * HD + p] = fmaf(Dh, xh, (ya0 + ya1) + (ya2 + ya3));
        dt = dt_n; xh = xh_n;
        #pragma unroll
        for (int q = 0; q < 4; ++q) { Bv[q] = Bn_[q]; Cv[q] = Cn_[q]; }
    }
    size_t sidx = ((((size_t)b * NH + h) * NCHUNK + c) * 32 + p) * 16;
    #pragma unroll
    for (int q = 0; q < 4; ++q) {
        f32x4 v; v[0]=s[q*4]; v[1]=s[q*4+1]; v[2]=s[q*4+2]; v[3]=s[q*4+3];
        *(f32x4*)(s_end + sidx + q * 4) = v;
    }
    if (p == 0) Pprod[(b * NH + h) * NCHUNK + c] = pr;
}

// ---------------- scan pass 2: combine chunk states -------------------------
__global__ __launch_bounds__(128) void scan2_k(const float* __restrict__ s_end,
        const float* __restrict__ Pprod, float* __restrict__ s_init) {
    int b  = blockIdx.x >> 2;
    int hq = blockIdx.x & 3;
    int h  = hq * 4 + (threadIdx.x >> 5);
    int p  = threadIdx.x & 31;
    float s[16];
    #pragma unroll
    for (int n = 0; n < 16; ++n) s[n] = 0.f;
    size_t bh = (size_t)b * NH + h;
    for (int c = 1; c < NCHUNK; ++c) {
        float P = Pprod[bh * NCHUNK + (c - 1)];
        size_t eidx = ((bh * NCHUNK + (c - 1)) * 32 + p) * 16;
        size_t iidx = ((bh * NCHUNK + c) * 32 + p) * 16;
        #pragma unroll
        for (int q = 0; q < 4; ++q) {
            f32x4 e = *(const f32x4*)(s_end + eidx + q * 4);
            f32x4 o;
            #pragma unroll
            for (int j = 0; j < 4; ++j) {
                s[q*4+j] = fmaf(P, s[q*4+j], e[j]);
                o[j] = s[q*4+j];
            }
            *(f32x4*)(s_init + iidx + q * 4) = o;
        }
    }
}

// ---------------- scan pass 3: y += cumdA * (C . s_init) --------------------
__global__ __launch_bounds__(128) void scan3_k(const float* __restrict__ xbc,
        const float* __restrict__ dtb, const float* __restrict__ A_log,
        const float* __restrict__ s_init, float* __restrict__ y) {
    int c   = (blockIdx.x % 7) + 1;
    int bhq = blockIdx.x / 7;
    int b   = bhq >> 2;
    int hq  = bhq & 3;
    int h   = hq * 4 + (threadIdx.x >> 5);
    int p   = threadIdx.x & 31;
    float A = -expf(A_log[h]);
    size_t iidx = ((((size_t)b * NH + h) * NCHUNK + c) * 32 + p) * 16;
    float si[16];
    #pragma unroll
    for (int q = 0; q < 4; ++q) {
        f32x4 v = *(const f32x4*)(s_init + iidx + q * 4);
        si[q*4] = v[0]; si[q*4+1] = v[1]; si[q*4+2] = v[2]; si[q*4+3] = v[3];
    }
    float cum = 1.f;
    int base = b * T_ + c * CLEN;
    for (int t = 0; t < CLEN; ++t) {
        int m = base + t;
        float dt = dtb[m * NH + h];
        cum *= expf(dt * A);
        const float* Cr = xbc + (size_t)m * CD + DI + DSZ;
        float dot = 0.f;
        #pragma unroll
        for (int q = 0; q < 4; ++q) {
            f32x4 Cv = *(const f32x4*)(Cr + q * 4);
            #pragma unroll
            for (int j = 0; j < 4; ++j) dot = fmaf(si[q*4+j], Cv[j], dot);
        }
        y[(size_t)m * DI + h * HD + p] += cum * dot;
    }
}

// ---------------- gated RMSNorm (wave/row of 512) -> A3 (hi|hi|lo, K=512) ---
__global__ __launch_bounds__(256) void gate_rms_k(const float* __restrict__ y,
        const float* __restrict__ zx, const float* __restrict__ nw,
        u16* __restrict__ A3) {
    int row = blockIdx.x * 4 + (threadIdx.x >> 6);
    int lane = threadIdx.x & 63;
    int e0 = lane * 4, e1 = 256 + lane * 4;
    const float* yr = y + (size_t)row * DI;
    const float* zr = zx + (size_t)row * DIP;
    f32x4 y0 = *(const f32x4*)(yr + e0);
    f32x4 y1 = *(const f32x4*)(yr + e1);
    f32x4 z0 = *(const f32x4*)(zr + e0);
    f32x4 z1 = *(const f32x4*)(zr + e1);
    f32x4 g0, g1;
    float sq = 0.f;
    #pragma unroll
    for (int j = 0; j < 4; ++j) {
        g0[j] = y0[j] * (z0[j] / (1.f + expf(-z0[j])));
        g1[j] = y1[j] * (z1[j] / (1.f + expf(-z1[j])));
        sq += g0[j] * g0[j] + g1[j] * g1[j];
    }
    sq = wave_sum(sq);
    float r = rsqrtf(sq * (1.f / DI) + 1e-5f);
    f32x4 w0 = *(const f32x4*)(nw + e0);
    f32x4 w1 = *(const f32x4*)(nw + e1);
    u16* ar = A3 + (size_t)row * 1536;
    short4v hi4, lo4;
    #pragma unroll
    for (int j = 0; j < 4; ++j) {
        float ov = g0[j] * r * w0[j];
        u16 hi, lo; split_bf(ov, hi, lo);
        hi4[j] = (short)hi; lo4[j] = (short)lo;
    }
    *(short4v*)(ar + e0) = hi4;
    *(short4v*)(ar + 512 + e0) = hi4;
    *(short4v*)(ar + 1024 + e0) = lo4;
    #pragma unroll
    for (int j = 0; j < 4; ++j) {
        float ov = g1[j] * r * w1[j];
        u16 hi, lo; split_bf(ov, hi, lo);
        hi4[j] = (short)hi; lo4[j] = (short)lo;
    }
    *(short4v*)(ar + e1) = hi4;
    *(short4v*)(ar + 512 + e1) = hi4;
    *(short4v*)(ar + 1024 + e1) = lo4;
}

// ---------------- h = LN(c + h) (wave/row of 256) -> h + A3 (K=256) ---------
__global__ __launch_bounds__(256) void add_ln_k(float* __restrict__ h,
        const float* __restrict__ c, const float* __restrict__ w,
        const float* __restrict__ bb, u16* __restrict__ A3) {
    int row = blockIdx.x * 4 + (threadIdx.x >> 6);
    int lane = threadIdx.x & 63;
    int e = lane * 4;
    float* hr = h + (size_t)row * DM;
    const float* cr = c + (size_t)row * DM;
    f32x4 v = *(const f32x4*)(hr + e);
    f32x4 vc = *(const f32x4*)(cr + e);
    float s = 0.f, sq = 0.f;
    #pragma unroll
    for (int j = 0; j < 4; ++j) {
        v[j] += vc[j];
        s += v[j];
        sq += v[j] * v[j];
    }
    s = wave_sum(s); sq = wave_sum(sq);
    float mean = s * (1.f / DM);
    float var = sq * (1.f / DM) - mean * mean;
    float r = rsqrtf(var + 1e-5f);
    f32x4 vw = *(const f32x4*)(w + e);
    f32x4 vb = *(const f32x4*)(bb + e);
    f32x4 o;
    short4v hi4, lo4;
    #pragma unroll
    for (int j = 0; j < 4; ++j) {
        float ov = (v[j] - mean) * r * vw[j] + vb[j];
        o[j] = ov;
        u16 hi, lo; split_bf(ov, hi, lo);
        hi4[j] = (short)hi; lo4[j] = (short)lo;
    }
    *(f32x4*)(hr + e) = o;
    u16* ar = A3 + (size_t)row * 768;
    *(short4v*)(ar + e) = hi4;
    *(short4v*)(ar + 256 + e) = hi4;
    *(short4v*)(ar + 512 + e) = lo4;
}

// ---------------- mean over time -------------------------------------------
__global__ __launch_bounds__(DM) void pool_k(const float* __restrict__ h,
                                             float* __restrict__ pooled) {
    int b = blockIdx.x, d = threadIdx.x;
    float s = 0.f;
    for (int t = 0; t < T_; ++t) s += h[(size_t)(b * T_ + t) * DM + d];
    pooled[b * DM + d] = s * (1.f / T_);
}

// ---------------- head: relu(pooled@W1^T+b1)@W2^T + b2 ----------------------
__global__ __launch_bounds__(128) void head_k(const float* __restrict__ pooled,
        const float* __restrict__ w1, const float* __restrict__ b1,
        const float* __restrict__ w2, const float* __restrict__ b2,
        float* __restrict__ out) {
    int b = blockIdx.x, j = threadIdx.x;
    const float* pr = pooled + b * DM;
    float acc = b1[j];
    for (int d = 0; d < DM; ++d) acc += pr[d] * w1[j * DM + d];
    float hid = fmaxf(acc, 0.f);
    float v = hid * w2[j];
    #pragma unroll
    for (int off = 32; off > 0; off >>= 1) v += __shfl_xor(v, off);
    __shared__ float red[2];
    if ((j & 63) == 0) red[j >> 6] = v;
    __syncthreads();
    if (j == 0) out[b] = red[0] + red[1] + b2[0];
}

extern "C" void kernel_launch(void* const* d_in, const int* in_sizes, int n_in,
                              void* d_out, int out_size, void* d_ws, size_t ws_size,
                              hipStream_t stream) {
    const float* x         = (const float*)d_in[0];
    const float* emb       = (const float*)d_in[1];
    const float* sconv_w   = (const float*)d_in[2];
    const float* sconv_b   = (const float*)d_in[3];
    const float* mixer_w   = (const float*)d_in[4];
    const float* mixer_b   = (const float*)d_in[5];
    const float* enc_ln_w  = (const float*)d_in[6];
    const float* enc_ln_b  = (const float*)d_in[7];
    const float* in_proj_w = (const float*)d_in[8];
    const float* conv_w    = (const float*)d_in[9];
    const float* conv_b    = (const float*)d_in[10];
    const float* dt_bias   = (const float*)d_in[11];
    const float* A_log     = (const float*)d_in[12];
    const float* D_skip    = (const float*)d_in[13];
    const float* norm_w    = (const float*)d_in[14];
    const float* out_proj_w= (const float*)d_in[15];
    const float* ln_w      = (const float*)d_in[16];
    const float* ln_b      = (const float*)d_in[17];
    const float* head1_w   = (const float*)d_in[18];
    const float* head1_b   = (const float*)d_in[19];
    const float* head2_w   = (const float*)d_in[20];
    const float* head2_b   = (const float*)d_in[21];
    float* out = (float*)d_out;

    float* ws  = (float*)d_ws;
    float* h   = ws;                          // M*DM
    float* zx  = h   + (size_t)M_TOT * DM;    // M*DIP
    float* xbc = zx  + (size_t)M_TOT * DIP;   // M*CD
    float* dtb = xbc + (size_t)M_TOT * CD;    // M*NH
    float* y   = dtb + (size_t)M_TOT * NH;    // M*DI
    float* em  = y   + (size_t)M_TOT * DI;    // 256
    float* pooled = em + 256;                 // 16,384
    u16* A3 = (u16*)(pooled + 16384);         // 12800*1536 u16
    u16* B3 = A3 + (size_t)12800 * 1536;      // 1152*768 u16 (max)

    // scan scratch aliases A3 (A3 dead during scan; rewritten by gate_rms)
    float* s_end  = (float*)A3;                       // 64*16*8*512 floats
    float* s_init = s_end + (size_t)B_*NH*NCHUNK*512; // same size
    float* Pprod  = s_init + (size_t)B_*NH*NCHUNK*512;// 8192 floats

    // ---- encoder ----
    emb_mean_k<<<1, DM, 0, stream>>>(emb, em);
    pack_b3_k<<<(DM * KENC + 255) / 256, 256, 0, stream>>>(mixer_w, B3, DM, DM, NCH_, KENC);
    xsA3_k<<<(M_TOT * KENC + 255) / 256, 256, 0, stream>>>(x, sconv_w, sconv_b, A3);
    gemm_mfma<<<2 * 100, 256, 0, stream>>>(A3, B3, h, 3 * KENC, DM, DM, 2);
    enc_ln_k<<<M_TOT / 4, 256, 0, stream>>>(h, mixer_b, em, enc_ln_w, enc_ln_b, A3);

    for (int l = 0; l < 4; ++l) {
        // in_proj: K=256 -> K3=768, N=1072 (pad 1152); A3 from enc_ln/add_ln
        pack_b3_k<<<(1152 * DM + 255) / 256, 256, 0, stream>>>(
            in_proj_w + (size_t)l * DIP * DM, B3, DIP, 1152, DM, DM);
        gemm_mfma<<<9 * 100, 256, 0, stream>>>(A3, B3, zx, 768, DIP, DIP, 9);

        dt_k<<<(M_TOT * NH + 255) / 256, 256, 0, stream>>>(zx, dt_bias + l * NH, dtb);
        conv_k<<<(M_TOT * CD + 255) / 256, 256, 0, stream>>>(
            zx, conv_w + l * CD * 4, conv_b + l * CD, xbc);

        scan1_k<<<B_ * 4 * NCHUNK, 128, 0, stream>>>(
            xbc, dtb, A_log + l * NH, D_skip + l * NH, y, s_end, Pprod);
        scan2_k<<<B_ * 4, 128, 0, stream>>>(s_end, Pprod, s_init);
        scan3_k<<<B_ * 4 * (NCHUNK - 1), 128, 0, stream>>>(
            xbc, dtb, A_log + l * NH, s_init, y);

        gate_rms_k<<<M_TOT / 4, 256, 0, stream>>>(y, zx, norm_w + l * DI, A3);

        // out_proj: K=512 -> K3=1536, N=256
        pack_b3_k<<<(DM * DI + 255) / 256, 256, 0, stream>>>(
            out_proj_w + (size_t)l * DM * DI, B3, DM, DM, DI, DI);
        gemm_mfma<<<2 * 100, 256, 0, stream>>>(A3, B3, zx, 1536, DM, DM, 2);

        add_ln_k<<<M_TOT / 4, 256, 0, stream>>>(h, zx, ln_w + l * DM, ln_b + l * DM, A3);
    }

    pool_k<<<B_, DM, 0, stream>>>(h, pooled);
    head_k<<<B_, 128, 0, stream>>>(pooled, head1_w, head1_b, head2_w, head2_b, out);
}